// Round 7
// baseline (372.270 us; speedup 1.0000x reference)
//
#include <hip/hip_runtime.h>
#include <math.h>

#define B_ 4
#define T_ 2048
#define C_ 1024
#define H_ 16
#define NROWS (B_*T_)   // 8192

typedef short s8v  __attribute__((ext_vector_type(8)));
typedef float f4v  __attribute__((ext_vector_type(4)));
typedef unsigned short u16v4 __attribute__((ext_vector_type(4)));

#define QSCALE 0.1803368801111f   // 0.125 * log2(e): scores in log2 domain

static __device__ __forceinline__ unsigned short f2bf(float x) {
    unsigned u = __float_as_uint(x);
    unsigned r = u + 0x7fffu + ((u >> 16) & 1u);
    return (unsigned short)(r >> 16);
}

static __device__ __forceinline__ float fexp2(float x) {
    return __builtin_amdgcn_exp2f(x);
}

static __device__ __forceinline__ void gload_lds16(const void* g, void* l) {
    __builtin_amdgcn_global_load_lds(
        (const __attribute__((address_space(1))) void*)g,
        (__attribute__((address_space(3))) void*)l, 16, 0, 0);
}

// ---- software grid barrier (all blocks co-resident by construction) ----
// bar[0]=arrival counter, bar[1]=generation; zeroed by prep_kernel each iter.
static __device__ __forceinline__ void gsync(int* bar, int nblk) {
    __syncthreads();
    __threadfence();
    if (threadIdx.x == 0) {
        int* cnt = bar;
        int* gen = bar + 1;
        int g = __hip_atomic_load(gen, __ATOMIC_ACQUIRE, __HIP_MEMORY_SCOPE_AGENT);
        int a = __hip_atomic_fetch_add(cnt, 1, __ATOMIC_ACQ_REL, __HIP_MEMORY_SCOPE_AGENT);
        if (a == nblk - 1) {
            __hip_atomic_store(cnt, 0, __ATOMIC_RELAXED, __HIP_MEMORY_SCOPE_AGENT);
            __hip_atomic_fetch_add(gen, 1, __ATOMIC_ACQ_REL, __HIP_MEMORY_SCOPE_AGENT);
        } else {
            while (__hip_atomic_load(gen, __ATOMIC_ACQUIRE, __HIP_MEMORY_SCOPE_AGENT) == g)
                __builtin_amdgcn_s_sleep(2);
        }
    }
    __syncthreads();
}

// ---- prep: LN1 row + qkv-weight cvt slice + zero imp/nsurv (grid NROWS) ----
__global__ __launch_bounds__(256) void prep_kernel(
        const float* __restrict__ x, const float* __restrict__ w,
        const float* __restrict__ b, unsigned short* __restrict__ out,
        const float* __restrict__ wsrc, unsigned short* __restrict__ wdst,
        float* __restrict__ imp, int* __restrict__ nsurv)
{
    int row = blockIdx.x;
    int tid = threadIdx.x;
    // qkv weight convert slice: 8192 blocks x 96 vec4 = 786432 = 3C*C/4
    int widx = row * 96 + tid;
    if (tid < 96) {
        float4 v = ((const float4*)wsrc)[widx];
        u16v4 o = { f2bf(v.x), f2bf(v.y), f2bf(v.z), f2bf(v.w) };
        *(u16v4*)(wdst + (size_t)widx*4) = o;
    }
    if (row < 32) imp[row*256 + tid] = 0.f;
    if (row == 32 && tid < 8) nsurv[tid] = 0;

    const float4* xr = (const float4*)(x + (size_t)row * C_);
    float4 v = xr[tid];
    float s  = v.x + v.y + v.z + v.w;
    float ss = v.x*v.x + v.y*v.y + v.z*v.z + v.w*v.w;
    #pragma unroll
    for (int off = 32; off > 0; off >>= 1) {
        s  += __shfl_down(s,  off, 64);
        ss += __shfl_down(ss, off, 64);
    }
    __shared__ float rs[4], rss[4];
    __shared__ float smu, srstd;
    int wave = tid >> 6, lane = tid & 63;
    if (lane == 0) { rs[wave] = s; rss[wave] = ss; }
    __syncthreads();
    if (tid == 0) {
        float S  = rs[0]+rs[1]+rs[2]+rs[3];
        float SS = rss[0]+rss[1]+rss[2]+rss[3];
        float mu = S * (1.0f/C_);
        float var = SS * (1.0f/C_) - mu*mu;
        smu = mu; srstd = rsqrtf(var + 1e-5f);
    }
    __syncthreads();
    float mu = smu, rstd = srstd;
    float4 wv = ((const float4*)w)[tid];
    float4 bv = ((const float4*)b)[tid];
    u16v4 o;
    o.x = f2bf((v.x-mu)*rstd*wv.x + bv.x);
    o.y = f2bf((v.y-mu)*rstd*wv.y + bv.y);
    o.z = f2bf((v.z-mu)*rstd*wv.z + bv.z);
    o.w = f2bf((v.w-mu)*rstd*wv.w + bv.w);
    *(u16v4*)(out + (size_t)row * C_ + tid*4) = o;
}

// ================= 256x256 8-phase QK GEMM (T1+T2+T3+T4+T5) =================
// M=8192 N=2048 K=1024 hard-coded. C = A (hbuf, MxK bf16) * Bw^T (NxK bf16),
// epilogue = bias + head-major q/k scatter (q pre-scaled by QSCALE).
#define STG(gbase_, ldsarr_, ah_, kt_, bb_) do { \
    gload_lds16(gbase_ + (size_t)((ah_)*128)*1024 + (kt_)*64, \
                &ldsarr_[bb_][(((ah_)*128) + (w<<3))*64]); \
    gload_lds16(gbase_ + (size_t)((ah_)*128 + 64)*1024 + (kt_)*64, \
                &ldsarr_[bb_][(((ah_)*128 + 64) + (w<<3))*64]); \
} while (0)

#define PHASE(ah_, bh_, ...) do { \
    s8v af[4][2], bf[2][2]; \
    _Pragma("unroll") \
    for (int i2 = 0; i2 < 4; i2++) { \
        int arow = ((ah_)*128 + wr*64 + i2*16 + l16)*64; \
        af[i2][0] = *(const s8v*)&As[bb][arow + (((quad)     ^ (l16&7))<<3)]; \
        af[i2][1] = *(const s8v*)&As[bb][arow + (((4 + quad) ^ (l16&7))<<3)]; \
    } \
    _Pragma("unroll") \
    for (int j2 = 0; j2 < 2; j2++) { \
        int brow = ((bh_)*128 + wc*32 + j2*16 + l16)*64; \
        bf[j2][0] = *(const s8v*)&Bs[bb][brow + (((quad)     ^ (l16&7))<<3)]; \
        bf[j2][1] = *(const s8v*)&Bs[bb][brow + (((4 + quad) ^ (l16&7))<<3)]; \
    } \
    __VA_ARGS__; \
    asm volatile("s_barrier" ::: "memory"); \
    asm volatile("s_waitcnt lgkmcnt(0)" ::: "memory"); \
    __builtin_amdgcn_sched_barrier(0); \
    __builtin_amdgcn_s_setprio(1); \
    _Pragma("unroll") \
    for (int i2 = 0; i2 < 4; i2++) \
        _Pragma("unroll") \
        for (int j2 = 0; j2 < 2; j2++) { \
            acc[(ah_)*4+i2][(bh_)*2+j2] = __builtin_amdgcn_mfma_f32_16x16x32_bf16( \
                af[i2][0], bf[j2][0], acc[(ah_)*4+i2][(bh_)*2+j2], 0, 0, 0); \
            acc[(ah_)*4+i2][(bh_)*2+j2] = __builtin_amdgcn_mfma_f32_16x16x32_bf16( \
                af[i2][1], bf[j2][1], acc[(ah_)*4+i2][(bh_)*2+j2], 0, 0, 0); \
        } \
    __builtin_amdgcn_s_setprio(0); \
    __builtin_amdgcn_sched_barrier(0); \
    asm volatile("s_barrier" ::: "memory"); \
} while (0)

__global__ __launch_bounds__(512, 2) void gemm_qk_8ph(
    const unsigned short* __restrict__ A,
    const unsigned short* __restrict__ Bw,
    const float* __restrict__ bias,
    unsigned short* __restrict__ qh, unsigned short* __restrict__ kh)
{
    __shared__ unsigned short As[2][256*64];   // 64 KiB
    __shared__ unsigned short Bs[2][256*64];   // 64 KiB

    const int tid  = threadIdx.x;
    const int w    = tid >> 6, lane = tid & 63;
    const int quad = lane >> 4, l16 = lane & 15;
    const int wr   = w >> 2, wc = w & 3;
    const int rl   = tid >> 3;                 // staging row within 64-row round
    const int kc   = (tid & 7) ^ (rl & 7);     // pre-swizzled source chunk

    // XCD-aware swizzle (T1): nwg=256, 8 XCDs, 256%8==0 -> simple bijection
    const int bid = blockIdx.x;
    const int vb  = (bid & 7) * 32 + (bid >> 3);
    const int m0  = (vb >> 3) << 8;            // 32 m-tiles
    const int n0  = (vb & 7) << 8;             // 8 n-tiles

    const unsigned short* gA0 = A  + (size_t)(m0 + rl) * 1024 + kc * 8;
    const unsigned short* gB0 = Bw + (size_t)(n0 + rl) * 1024 + kc * 8;

    // prologue: tile0 complete (oldest 8 loads), then A0/B1 of tile1
    STG(gA0, As, 0, 0, 0);
    STG(gB0, Bs, 1, 0, 0);
    STG(gA0, As, 1, 0, 0);
    STG(gB0, Bs, 0, 0, 0);
    STG(gA0, As, 0, 1, 1);
    STG(gB0, Bs, 1, 1, 1);

    f4v acc[8][4];
    #pragma unroll
    for (int i = 0; i < 8; i++)
        #pragma unroll
        for (int j = 0; j < 4; j++) {
            acc[i][j][0] = 0.f; acc[i][j][1] = 0.f;
            acc[i][j][2] = 0.f; acc[i][j][3] = 0.f;
        }

    #pragma unroll 2
    for (int t = 0; t < 16; ++t) {
        const int bb = t & 1, nb = bb ^ 1;
        if (t < 15) asm volatile("s_waitcnt vmcnt(4)" ::: "memory");
        else        asm volatile("s_waitcnt vmcnt(0)" ::: "memory");
        asm volatile("s_barrier" ::: "memory");
        __builtin_amdgcn_sched_barrier(0);
        PHASE(0, 0, if (t < 15) STG(gA0, As, 1, t+1, nb));
        PHASE(0, 1, if (t < 15) STG(gB0, Bs, 0, t+1, nb));
        PHASE(1, 1, if (t < 14) STG(gA0, As, 0, t+2, bb));
        PHASE(1, 0, if (t < 14) STG(gB0, Bs, 1, t+2, bb));
    }

    // epilogue: bias + head-major scatter (EPI3 semantics, ncoff=0, N=2048)
    #pragma unroll
    for (int j = 0; j < 4; j++) {
        int ncol = n0 + ((j >> 1) << 7) + (wc << 5) + ((j & 1) << 4) + l16;
        float bv = bias[ncol];
        int sec = ncol >> 10;
        int hh = (ncol & 1023) >> 6, dd = ncol & 63;
        unsigned short* basep = (sec == 0) ? qh : kh;
        bool qsec = (sec == 0);
        #pragma unroll
        for (int i = 0; i < 8; i++) {
            int mbase = m0 + ((i >> 2) << 7) + (wr << 6) + ((i & 3) << 4) + (quad << 2);
            #pragma unroll
            for (int reg = 0; reg < 4; reg++) {
                int m = mbase + reg;
                float v = acc[i][j][reg] + bv;
                if (qsec) v *= QSCALE;
                int b_ = m >> 11, tt = m & 2047;
                basep[(((size_t)(b_*H_ + hh))*T_ + tt)*64 + dd] = f2bf(v);
            }
        }
    }
}

// ---------------- attention pass 1: linv[bh][q] = 1/sum_k exp2(s) ----------------
// (round-4 proven-best) K-fragment loads register double-buffered at qt-tile
// granularity: loads for tile it+4 issue BEFORE compute of tile it
// (32 MFMA + 64 exp2 ~ 700+ cyc), hiding the L2/L3 load latency.
#define RS_LOADK(K_, it_) do { \
    int k0_ = (it_) * 64; \
    _Pragma("unroll") \
    for (int c_ = 0; c_ < 2; c_++) \
        _Pragma("unroll") \
        for (int nt_ = 0; nt_ < 4; nt_++) \
            K_[c_][nt_] = *(const s8v*)(kp + (size_t)(k0_ + nt_*16 + l16)*64 + c_*32 + quad*8); \
} while (0)

#define RS_COMP(K_, it_) do { \
    int k0_ = (it_) * 64; \
    float mk[4]; \
    _Pragma("unroll") \
    for (int nt_ = 0; nt_ < 4; nt_++) mk[nt_] = msk01[k0_ + nt_*16 + l16]; \
    bool allm = __all(mk[0] != 0.f && mk[1] != 0.f && mk[2] != 0.f && mk[3] != 0.f); \
    _Pragma("unroll") \
    for (int qf = 0; qf < 4; qf++) { \
        f4v acc[4]; \
        _Pragma("unroll") \
        for (int nt_ = 0; nt_ < 4; nt_++) { acc[nt_][0]=0.f; acc[nt_][1]=0.f; acc[nt_][2]=0.f; acc[nt_][3]=0.f; } \
        _Pragma("unroll") \
        for (int c_ = 0; c_ < 2; c_++) \
            _Pragma("unroll") \
            for (int nt_ = 0; nt_ < 4; nt_++) \
                acc[nt_] = __builtin_amdgcn_mfma_f32_16x16x32_bf16(aQ[qf][c_], K_[c_][nt_], acc[nt_], 0, 0, 0); \
        if ((it_) < qt && allm) { \
            _Pragma("unroll") \
            for (int nt_ = 0; nt_ < 4; nt_++) \
                _Pragma("unroll") \
                for (int reg = 0; reg < 4; reg++) \
                    lrow[qf][reg] += fexp2(acc[nt_][reg]); \
        } else if ((it_) < qt) { \
            _Pragma("unroll") \
            for (int nt_ = 0; nt_ < 4; nt_++) \
                _Pragma("unroll") \
                for (int reg = 0; reg < 4; reg++) \
                    lrow[qf][reg] += fexp2(acc[nt_][reg]) * mk[nt_]; \
        } else { \
            _Pragma("unroll") \
            for (int nt_ = 0; nt_ < 4; nt_++) { \
                int kg = k0_ + nt_*16 + l16; \
                _Pragma("unroll") \
                for (int reg = 0; reg < 4; reg++) { \
                    float me = (kg <= q0 + qf*16 + quad*4 + reg) ? mk[nt_] : 0.f; \
                    lrow[qf][reg] += fexp2(acc[nt_][reg]) * me; \
                } \
            } \
        } \
    } \
} while (0)

__global__ __launch_bounds__(256) void attn_rowsum(
    const unsigned short* __restrict__ qh, const unsigned short* __restrict__ kh,
    const float* __restrict__ amask, float* __restrict__ linvbuf)
{
    __shared__ float msk01[2048];
    __shared__ float lred[4][64];

    int tid = threadIdx.x;
    int w = tid >> 6, lane = tid & 63, quad = lane >> 4, l16 = lane & 15;
    int qt = 31 - (blockIdx.x >> 6);     // heavy blocks first
    int bh = blockIdx.x & 63;
    int b  = bh >> 4;
    int q0 = qt * 64;
    int ntiles = qt + 1;

    const unsigned short* qp = qh + (size_t)bh*T_*64;
    const unsigned short* kp = kh + (size_t)bh*T_*64;
    const float* amp = amask + b*T_;

    for (int i = tid; i < ntiles*64; i += 256)
        msk01[i] = (amp[i] != 0.f) ? 1.f : 0.f;

    s8v aQ[4][2];
    #pragma unroll
    for (int qf = 0; qf < 4; qf++) {
        int row = q0 + qf*16 + l16;
        aQ[qf][0] = *(const s8v*)(qp + (size_t)row*64 + quad*8);
        aQ[qf][1] = *(const s8v*)(qp + (size_t)row*64 + 32 + quad*8);
    }

    float lrow[4][4];
    #pragma unroll
    for (int qf = 0; qf < 4; qf++)
        #pragma unroll
        for (int reg = 0; reg < 4; reg++) lrow[qf][reg] = 0.f;

    s8v K0[2][4], K1[2][4];
    int it = w;
    if (it < ntiles) RS_LOADK(K0, it);
    __syncthreads();                     // msk01 ready
    if (it < ntiles) {
        while (true) {
            int itn = it + 4;
            if (itn < ntiles) {
                RS_LOADK(K1, itn);
                RS_COMP(K0, it);
                int it2 = itn + 4;
                if (it2 < ntiles) {
                    RS_LOADK(K0, it2);
                    RS_COMP(K1, itn);
                    it = it2;
                    continue;
                } else {
                    RS_COMP(K1, itn);
                    break;
                }
            } else {
                RS_COMP(K0, it);
                break;
            }
        }
    }

    #pragma unroll
    for (int qf = 0; qf < 4; qf++)
        #pragma unroll
        for (int reg = 0; reg < 4; reg++) {
            float v = lrow[qf][reg];
            v += __shfl_xor(v, 1); v += __shfl_xor(v, 2);
            v += __shfl_xor(v, 4); v += __shfl_xor(v, 8);
            lrow[qf][reg] = v;
        }
    if (l16 == 0) {
        #pragma unroll
        for (int qf = 0; qf < 4; qf++)
            #pragma unroll
            for (int reg = 0; reg < 4; reg++)
                lred[w][qf*16 + quad*4 + reg] = lrow[qf][reg];
    }
    __syncthreads();
    if (tid < 64) {
        float t = lred[0][tid] + lred[1][tid] + lred[2][tid] + lred[3][tid];
        linvbuf[(size_t)bh*T_ + q0 + tid] = (t > 0.f) ? 1.0f / t : 0.f;
    }
}

// ---------------- attention pass 2: imp[b][k] += sum_{h,q} exp2(s)*linv ----------------
// (round-4 proven-best) Ping-pong at FULL qt-tile granularity: stage all 4 qf
// Q-fragments + 4 linv4 for tile qt+4 before computing tile qt's 32 MFMA +
// 64 exp2 -- the big compute stage hides the L2/L3 latency.
#define CS_LOADQT(AQ_, LV_, qt_) do { \
    _Pragma("unroll") \
    for (int qf_ = 0; qf_ < 4; qf_++) { \
        int row_ = (qt_)*64 + qf_*16 + l16; \
        AQ_[qf_][0] = *(const s8v*)(qp + (size_t)row_*64 + quad*8); \
        AQ_[qf_][1] = *(const s8v*)(qp + (size_t)row_*64 + 32 + quad*8); \
        LV_[qf_] = *(const float4*)(lp + (qt_)*64 + qf_*16 + quad*4); \
    } \
} while (0)

#define CS_COMPQT(AQ_, LV_, qt_) do { \
    if ((qt_) > kc) { \
        _Pragma("unroll") \
        for (int qf_ = 0; qf_ < 4; qf_++) { \
            f4v acc[4]; \
            _Pragma("unroll") \
            for (int nt_ = 0; nt_ < 4; nt_++) { acc[nt_][0]=0.f; acc[nt_][1]=0.f; acc[nt_][2]=0.f; acc[nt_][3]=0.f; } \
            _Pragma("unroll") \
            for (int nt_ = 0; nt_ < 4; nt_++) { \
                acc[nt_] = __builtin_amdgcn_mfma_f32_16x16x32_bf16(AQ_[qf_][0], bk[0][nt_], acc[nt_], 0, 0, 0); \
                acc[nt_] = __builtin_amdgcn_mfma_f32_16x16x32_bf16(AQ_[qf_][1], bk[1][nt_], acc[nt_], 0, 0, 0); \
            } \
            float lv[4] = { LV_[qf_].x, LV_[qf_].y, LV_[qf_].z, LV_[qf_].w }; \
            _Pragma("unroll") \
            for (int nt_ = 0; nt_ < 4; nt_++) \
                _Pragma("unroll") \
                for (int reg = 0; reg < 4; reg++) \
                    cs[nt_] += fexp2(acc[nt_][reg]) * lv[reg]; \
        } \
    } else { \
        _Pragma("unroll") \
        for (int qf_ = 0; qf_ < 4; qf_++) { \
            f4v acc[4]; \
            _Pragma("unroll") \
            for (int nt_ = 0; nt_ < 4; nt_++) { acc[nt_][0]=0.f; acc[nt_][1]=0.f; acc[nt_][2]=0.f; acc[nt_][3]=0.f; } \
            _Pragma("unroll") \
            for (int nt_ = 0; nt_ < 4; nt_++) { \
                acc[nt_] = __builtin_amdgcn_mfma_f32_16x16x32_bf16(AQ_[qf_][0], bk[0][nt_], acc[nt_], 0, 0, 0); \
                acc[nt_] = __builtin_amdgcn_mfma_f32_16x16x32_bf16(AQ_[qf_][1], bk[1][nt_], acc[nt_], 0, 0, 0); \
            } \
            float lv[4] = { LV_[qf_].x, LV_[qf_].y, LV_[qf_].z, LV_[qf_].w }; \
            _Pragma("unroll") \
            for (int nt_ = 0; nt_ < 4; nt_++) { \
                int kg = k0 + nt_*16 + l16; \
                _Pragma("unroll") \
                for (int reg = 0; reg < 4; reg++) { \
                    float me = (kg <= (qt_)*64 + qf_*16 + quad*4 + reg) ? 1.f : 0.f; \
                    cs[nt_] += fexp2(acc[nt_][reg]) * lv[reg] * me; \
                } \
            } \
        } \
    } \
} while (0)

__global__ __launch_bounds__(256) void attn_colsum(
    const unsigned short* __restrict__ qh, const unsigned short* __restrict__ kh,
    const float* __restrict__ amask, const float* __restrict__ linvbuf,
    float* __restrict__ imp)
{
    __shared__ float cred[4][64];

    int tid = threadIdx.x;
    int w = tid >> 6, lane = tid & 63, quad = lane >> 4, l16 = lane & 15;
    int kc = blockIdx.x >> 6;
    int bh = blockIdx.x & 63;
    int b  = bh >> 4;
    int k0 = kc * 64;

    const unsigned short* qp = qh + (size_t)bh*T_*64;
    const unsigned short* kp = kh + (size_t)bh*T_*64;
    const float* lp = linvbuf + (size_t)bh*T_;

    s8v bk[2][4];
    float mk[4];
    #pragma unroll
    for (int nt = 0; nt < 4; nt++) {
        int key = k0 + nt*16 + l16;
        bk[0][nt] = *(const s8v*)(kp + (size_t)key*64 + quad*8);
        bk[1][nt] = *(const s8v*)(kp + (size_t)key*64 + 32 + quad*8);
        mk[nt] = amask[b*T_ + key];
    }

    float cs[4] = {0.f, 0.f, 0.f, 0.f};

    int qt = kc + w;
    if (qt < 32) {
        s8v AQa[4][2], AQb[4][2];
        float4 LVa[4], LVb[4];
        CS_LOADQT(AQa, LVa, qt);
        while (true) {
            int qtn = qt + 4;
            if (qtn < 32) {
                CS_LOADQT(AQb, LVb, qtn);
                CS_COMPQT(AQa, LVa, qt);
                int qt2 = qtn + 4;
                if (qt2 < 32) {
                    CS_LOADQT(AQa, LVa, qt2);
                    CS_COMPQT(AQb, LVb, qtn);
                    qt = qt2;
                    continue;
                } else {
                    CS_COMPQT(AQb, LVb, qtn);
                    break;
                }
            } else {
                CS_COMPQT(AQa, LVa, qt);
                break;
            }
        }
    }

    #pragma unroll
    for (int nt = 0; nt < 4; nt++) {
        float v = cs[nt] * mk[nt];
        v += __shfl_xor(v, 16);
        v += __shfl_xor(v, 32);
        if (quad == 0) cred[w][nt*16 + l16] = v;
    }
    __syncthreads();
    if (tid < 64)
        atomicAdd(&imp[b*T_ + k0 + tid],
                  cred[0][tid] + cred[1][tid] + cred[2][tid] + cred[3][tid]);
}

// ---------------- mask finalize: cm, loss, survivor count ----------------
__global__ __launch_bounds__(256) void mask_finalize(
    const float* __restrict__ imp, const float* __restrict__ amask,
    const float* __restrict__ prot, const float* __restrict__ thr,
    float* __restrict__ mask_out, float* __restrict__ loss_out,
    int* __restrict__ nsurv)
{
    int i = blockIdx.x * 256 + threadIdx.x;
    float impv = imp[i] * (1.0f / (float)(H_ * T_));
    float pm = (impv >= thr[0]) ? 1.f : 0.f;
    if (prot[i] > 0.f) pm = 1.f;
    float cm = amask[i] * pm;
    mask_out[i] = cm;
    if (i == 0) loss_out[0] = 0.f;
    unsigned long long bal = __ballot(cm != 0.f);
    int cnt = __popcll(bal);
    __shared__ int bs;
    if (threadIdx.x == 0) bs = 0;
    __syncthreads();
    if ((threadIdx.x & 63) == 0 && cnt) atomicAdd(&bs, cnt);
    __syncthreads();
    if (threadIdx.x == 0 && bs) atomicAdd(nsurv, bs);
}

// ================== consolidated tail (plain kernel + software grid barrier) ==================
// Replaces 12 flagged launches (cvt3, gemm x6, attn_full, ln, ap x3) with one
// plain kernel. Grid = 256 blocks x 256 threads, 32 KiB LDS: every CU can
// host >=1 block even at max VGPR -> all blocks co-resident -> spin barrier
// cannot deadlock. nsurv[0] is grid-uniform -> branch uniform -> consistent
// barrier counts per path. Barrier counters nsurv[4..5] zeroed by prep.

static __device__ void cvt3_body(
        const float* __restrict__ cprojw, const float* __restrict__ fcw,
        const float* __restrict__ fcpw,
        unsigned short* __restrict__ wproj, unsigned short* __restrict__ wfc,
        unsigned short* __restrict__ wfcp)
{
    const int total = 9*C_*C_/4;
    const int n1 = C_*C_/4;
    const int n2 = n1 + C_*C_;
    for (int i = blockIdx.x * 256 + threadIdx.x; i < total; i += gridDim.x * 256) {
        const float* src; unsigned short* dst; int j;
        if (i < n1)      { src = cprojw; dst = wproj; j = i; }
        else if (i < n2) { src = fcw;    dst = wfc;   j = i - n1; }
        else             { src = fcpw;   dst = wfcp;  j = i - n2; }
        float4 v = ((const float4*)src)[j];
        u16v4 o = { f2bf(v.x), f2bf(v.y), f2bf(v.z), f2bf(v.w) };
        *(u16v4*)(dst + (size_t)j*4) = o;
    }
}

// EPI: 1 = bias + exact GELU -> bf16 ; 2 = bias(opt) + fp32 residual -> fp32
//      3 = bias -> bf16 head-major qkv scatter (q pre-scaled by QSCALE)
//      4 = bias + (res + v)*cm -> fp32
template<int EPI>
static __device__ void gemm_body(
    unsigned short* As, unsigned short* Bs,
    const unsigned short* __restrict__ A,
    const unsigned short* __restrict__ Bw,
    const float* __restrict__ bias,
    const float* __restrict__ res,
    float* __restrict__ Cout, unsigned short* __restrict__ Cbf,
    int K, int lda, int ldb, int ldc, int ncoff,
    const float* __restrict__ cmv,
    unsigned short* __restrict__ qh, unsigned short* __restrict__ kh,
    unsigned short* __restrict__ vh,
    int nbx, int nby)
{
    int tid = threadIdx.x;
    int w = tid >> 6, lane = tid & 63, quad = lane >> 4, l16 = lane & 15;
    int wr = w >> 1, wc = w & 1;

    int nvb = nbx * nby;
    int vb0 = blockIdx.x;
    int vstride = gridDim.x;

    for (int vb = vb0; vb < nvb; vb += vstride) {
        int n0 = (vb % nbx) * 128;
        int m0 = (vb / nbx) * 128;

        size_t offA[4], offB[4];
        #pragma unroll
        for (int j = 0; j < 4; j++) {
            int ci = j*256 + tid;
            int mr = ci >> 3, kcs = ci & 7;
            int kc = kcs ^ (mr & 7);
            offA[j] = (size_t)(m0 + mr) * lda + kc*8;
            offB[j] = (size_t)(n0 + mr) * ldb + kc*8;
        }

        f4v acc[4][4];
        #pragma unroll
        for (int i = 0; i < 4; i++)
            #pragma unroll
            for (int j = 0; j < 4; j++) { acc[i][j][0]=0.f; acc[i][j][1]=0.f; acc[i][j][2]=0.f; acc[i][j][3]=0.f; }

        for (int k0 = 0; k0 < K; k0 += 64) {
            __syncthreads();
            #pragma unroll
            for (int j = 0; j < 4; j++) {
                gload_lds16(A  + offA[j] + k0, &As[(j*256 + (w<<6))*8]);
                gload_lds16(Bw + offB[j] + k0, &Bs[(j*256 + (w<<6))*8]);
            }
            __syncthreads();
            #pragma unroll
            for (int c = 0; c < 2; c++) {
                s8v af[4], bf[4];
                int sw = ((c<<2) + quad) ^ (l16 & 7);
                #pragma unroll
                for (int i = 0; i < 4; i++) {
                    int mr = wr*64 + i*16 + l16;
                    af[i] = *(const s8v*)&As[mr*64 + sw*8];
                    int nr = wc*64 + i*16 + l16;
                    bf[i] = *(const s8v*)&Bs[nr*64 + sw*8];
                }
                #pragma unroll
                for (int i = 0; i < 4; i++)
                    #pragma unroll
                    for (int j = 0; j < 4; j++)
                        acc[i][j] = __builtin_amdgcn_mfma_f32_16x16x32_bf16(af[i], bf[j], acc[i][j], 0, 0, 0);
            }
        }

        #pragma unroll
        for (int j = 0; j < 4; j++) {
            int ncol = n0 + wc*64 + j*16 + l16;
            float bv = bias ? bias[ncol] : 0.f;
            int hh = 0, dd = 0;
            bool qsec = false;
            unsigned short* basep = nullptr;
            if (EPI == 3) {
                int ncolg = ncol + ncoff;
                int sec = ncolg >> 10;
                int hn = ncolg & 1023;
                hh = hn >> 6; dd = hn & 63;
                basep = (sec == 0) ? qh : (sec == 1) ? kh : vh;
                qsec = (sec == 0);
            }
            #pragma unroll
            for (int i = 0; i < 4; i++) {
                #pragma unroll
                for (int reg = 0; reg < 4; reg++) {
                    int m = m0 + wr*64 + i*16 + quad*4 + reg;
                    float v = acc[i][j][reg] + bv;
                    if (EPI == 1) {
                        v = 0.5f * v * (1.0f + erff(v * 0.70710678118654752f));
                        Cbf[(size_t)m*ldc + ncol] = f2bf(v);
                    } else if (EPI == 2) {
                        Cout[(size_t)m*ldc + ncol] = v + res[(size_t)m*ldc + ncol];
                    } else if (EPI == 3) {
                        if (qsec) v *= QSCALE;
                        int bb = m >> 11, t = m & 2047;
                        basep[(((size_t)(bb*H_ + hh))*T_ + t)*64 + dd] = f2bf(v);
                    } else if (EPI == 4) {
                        Cout[(size_t)m*ldc + ncol] = (res[(size_t)m*ldc + ncol] + v) * cmv[m];
                    }
                }
            }
        }
        __syncthreads();
    }
}

static __device__ void attn_full_body(unsigned short* sm,
    const unsigned short* __restrict__ qh, const unsigned short* __restrict__ kh,
    const unsigned short* __restrict__ vh, const float* __restrict__ amask,
    unsigned short* __restrict__ y)
{
    // layout in sm (shorts): Ks[64*72] | Vt[64*72] | Ps[4*16*72] | mks(64 fl)
    unsigned short* Ks = sm;
    unsigned short* Vt = sm + 64*72;
    unsigned short* Ps = sm + 2*64*72;
    float* mks = (float*)(sm + 2*64*72 + 4*16*72);

    int tid = threadIdx.x;
    int w = tid >> 6, lane = tid & 63, quad = lane >> 4, l16 = lane & 15;
    int nqt = T_ / 64;

    for (int vb = blockIdx.x; vb < B_*H_*nqt; vb += gridDim.x) {
        int qt = vb % nqt;
        int bh = vb / nqt;
        int b = bh >> 4, h = bh & 15;
        int q0 = qt * 64;

        const unsigned short* qp = qh + (size_t)bh * T_ * 64;
        const unsigned short* kp = kh + (size_t)bh * T_ * 64;
        const unsigned short* vp = vh + (size_t)bh * T_ * 64;

        int qrow = q0 + 16*w + l16;
        s8v aQ0 = *(const s8v*)(qp + (size_t)qrow*64 + quad*8);
        s8v aQ1 = *(const s8v*)(qp + (size_t)qrow*64 + 32 + quad*8);

        int qwmax = q0 + 16*w + 15;
        int ntiles = qt + 1;
        int qg = q0 + 16*w + quad*4;

        float lrow[4] = {0.f, 0.f, 0.f, 0.f};
        for (int it = 0; it < ntiles; ++it) {
            int k0 = it * 64;
            __syncthreads();
            for (int cid = tid; cid < 512; cid += 256) {
                int row = cid >> 3, ch = cid & 7;
                *(s8v*)&Ks[row*72 + ch*8] = *(const s8v*)(kp + (size_t)(k0+row)*64 + ch*8);
            }
            if (tid < 64) mks[tid] = amask[b*T_ + k0 + tid];
            __syncthreads();
            if (k0 > qwmax) continue;
            f4v accS[4];
            #pragma unroll
            for (int nt = 0; nt < 4; nt++) { accS[nt][0]=0.f; accS[nt][1]=0.f; accS[nt][2]=0.f; accS[nt][3]=0.f; }
            #pragma unroll
            for (int nt = 0; nt < 4; nt++) {
                s8v b0 = *(const s8v*)&Ks[(nt*16 + l16)*72 + quad*8];
                s8v b1 = *(const s8v*)&Ks[(nt*16 + l16)*72 + 32 + quad*8];
                accS[nt] = __builtin_amdgcn_mfma_f32_16x16x32_bf16(aQ0, b0, accS[nt], 0, 0, 0);
                accS[nt] = __builtin_amdgcn_mfma_f32_16x16x32_bf16(aQ1, b1, accS[nt], 0, 0, 0);
            }
            #pragma unroll
            for (int nt = 0; nt < 4; nt++) {
                int kg = k0 + nt*16 + l16;
                float mkv = mks[nt*16 + l16];
                #pragma unroll
                for (int reg = 0; reg < 4; reg++) {
                    bool val = (kg <= qg + reg) && (mkv != 0.f);
                    float e = fexp2(accS[nt][reg]);
                    lrow[reg] += val ? e : 0.f;
                }
            }
        }
        float linv[4];
        #pragma unroll
        for (int reg = 0; reg < 4; reg++) {
            float v = lrow[reg];
            v += __shfl_xor(v, 1); v += __shfl_xor(v, 2);
            v += __shfl_xor(v, 4); v += __shfl_xor(v, 8);
            linv[reg] = (v > 0.f) ? 1.0f / v : 0.f;
        }

        f4v accO[4];
        #pragma unroll
        for (int nt = 0; nt < 4; nt++) { accO[nt][0]=0.f; accO[nt][1]=0.f; accO[nt][2]=0.f; accO[nt][3]=0.f; }

        for (int it = 0; it < ntiles; ++it) {
            int k0 = it * 64;
            __syncthreads();
            for (int cid = tid; cid < 512; cid += 256) {
                int row = cid >> 3, ch = cid & 7;
                s8v kv = *(const s8v*)(kp + (size_t)(k0+row)*64 + ch*8);
                *(s8v*)&Ks[row*72 + ch*8] = kv;
                s8v vv = *(const s8v*)(vp + (size_t)(k0+row)*64 + ch*8);
                #pragma unroll
                for (int j = 0; j < 8; j++) Vt[(ch*8 + j)*72 + row] = (unsigned short)vv[j];
            }
            if (tid < 64) mks[tid] = amask[b*T_ + k0 + tid];
            __syncthreads();
            if (k0 > qwmax) continue;
            f4v accS[4];
            #pragma unroll
            for (int nt = 0; nt < 4; nt++) { accS[nt][0]=0.f; accS[nt][1]=0.f; accS[nt][2]=0.f; accS[nt][3]=0.f; }
            #pragma unroll
            for (int nt = 0; nt < 4; nt++) {
                s8v b0 = *(const s8v*)&Ks[(nt*16 + l16)*72 + quad*8];
                s8v b1 = *(const s8v*)&Ks[(nt*16 + l16)*72 + 32 + quad*8];
                accS[nt] = __builtin_amdgcn_mfma_f32_16x16x32_bf16(aQ0, b0, accS[nt], 0, 0, 0);
                accS[nt] = __builtin_amdgcn_mfma_f32_16x16x32_bf16(aQ1, b1, accS[nt], 0, 0, 0);
            }
            #pragma unroll
            for (int nt = 0; nt < 4; nt++) {
                int kg = k0 + nt*16 + l16;
                float mkv = mks[nt*16 + l16];
                #pragma unroll
                for (int reg = 0; reg < 4; reg++) {
                    bool val = (kg <= qg + reg) && (mkv != 0.f);
                    float p = val ? fexp2(accS[nt][reg]) * linv[reg] : 0.f;
                    Ps[(w*16 + quad*4 + reg)*72 + nt*16 + l16] = f2bf(p);
                }
            }
            s8v aP0 = *(const s8v*)&Ps[(w*16 + l16)*72 + quad*8];
            s8v aP1 = *(const s8v*)&Ps[(w*16 + l16)*72 + 32 + quad*8];
            #pragma unroll
            for (int nt = 0; nt < 4; nt++) {
                s8v bv0 = *(const s8v*)&Vt[(nt*16 + l16)*72 + quad*8];
                s8v bv1 = *(const s8v*)&Vt[(nt*16 + l16)*72 + 32 + quad*8];
                accO[nt] = __builtin_amdgcn_mfma_f32_16x16x32_bf16(aP0, bv0, accO[nt], 0, 0, 0);
                accO[nt] = __builtin_amdgcn_mfma_f32_16x16x32_bf16(aP1, bv1, accO[nt], 0, 0, 0);
            }
        }
        #pragma unroll
        for (int nt = 0; nt < 4; nt++) {
            #pragma unroll
            for (int reg = 0; reg < 4; reg++) {
                int q = q0 + 16*w + quad*4 + reg;
                y[((size_t)(b*T_ + q))*C_ + h*64 + nt*16 + l16] = f2bf(accO[nt][reg]);
            }
        }
        __syncthreads();
    }
}

static __device__ void ln_body(const float* __restrict__ x,
        const float* __restrict__ w, const float* __restrict__ b,
        unsigned short* __restrict__ out, int nrows)
{
    int tid = threadIdx.x;
    __shared__ float rs[4], rss[4];
    __shared__ float smu, srstd;
    int wave = tid >> 6, lane = tid & 63;
    for (int row = blockIdx.x; row < nrows; row += gridDim.x) {
        const float4* xr = (const float4*)(x + (size_t)row * C_);
        float4 v = xr[tid];
        float s  = v.x + v.y + v.z + v.w;
        float ss = v.x*v.x + v.y*v.y + v.z*v.z + v.w*v.w;
        #pragma unroll
        for (int off = 32; off > 0; off >>= 1) {
            s  += __shfl_down(s,  off, 64);
            ss += __shfl_down(ss, off, 64);
        }
        if (lane == 0) { rs[wave] = s; rss[wave] = ss; }
        __syncthreads();
        if (tid == 0) {
            float S  = rs[0]+rs[1]+rs[2]+rs[3];
            float SS = rss[0]+rss[1]+rss[2]+rss[3];
            float mu = S * (1.0f/C_);
            float var = SS * (1.0f/C_) - mu*mu;
            smu = mu; srstd = rsqrtf(var + 1e-5f);
        }
        __syncthreads();
        float mu = smu, rstd = srstd;
        float4 wv = ((const float4*)w)[tid];
        float4 bv = ((const float4*)b)[tid];
        u16v4 o;
        o.x = f2bf((v.x-mu)*rstd*wv.x + bv.x);
        o.y = f2bf((v.y-mu)*rstd*wv.y + bv.y);
        o.z = f2bf((v.z-mu)*rstd*wv.z + bv.z);
        o.w = f2bf((v.w-mu)*rstd*wv.w + bv.w);
        *(u16v4*)(out + (size_t)row * C_ + tid*4) = o;
        __syncthreads();
    }
}

__global__ __launch_bounds__(256) void tail_kernel(
    const float* __restrict__ x, const float* __restrict__ amask,
    const float* __restrict__ cproj_w, const float* __restrict__ cproj_b,
    const float* __restrict__ ln2w, const float* __restrict__ ln2b,
    const float* __restrict__ fcw, const float* __restrict__ fcb,
    const float* __restrict__ fcpw, const float* __restrict__ fcpb,
    const float* __restrict__ cattn_b,
    unsigned short* __restrict__ wqkv, unsigned short* __restrict__ wproj,
    unsigned short* __restrict__ wfc, unsigned short* __restrict__ wfcp,
    unsigned short* __restrict__ hbuf,
    unsigned short* __restrict__ qh, unsigned short* __restrict__ kh,
    unsigned short* __restrict__ vh, unsigned short* __restrict__ cbuf,
    float* __restrict__ out_x, float* __restrict__ out_mask,
    int* __restrict__ nsurv, float* __restrict__ abuf,
    float* __restrict__ rowbuf)
{
    __shared__ unsigned short smem[2*128*64];   // 32 KiB, reused across phases
    unsigned short* As = smem;
    unsigned short* Bs = smem + 128*64;
    int* bar = nsurv + 4;                        // [cnt, gen], zeroed by prep
    const int nblk = gridDim.x;

    const bool dense = (nsurv[0] != 0);
    int tid = threadIdx.x, w = tid >> 6, lane = tid & 63;

    if (dense) {
        // ---- dense fallback path (replica of the former 9 launches) ----
        cvt3_body(cproj_w, fcw, fcpw, wproj, wfc, wfcp);
        // independent of the V-projection below: no barrier needed between
        gemm_body<3>(As, Bs, hbuf, wqkv + (size_t)2048*C_, cattn_b + 2048,
                     nullptr, nullptr, nullptr, C_, C_, C_, 0, 2048, nullptr,
                     qh, kh, vh, 8, 64);
        gsync(bar, nblk);
        attn_full_body(smem, qh, kh, vh, amask, hbuf);
        gsync(bar, nblk);
        gemm_body<4>(As, Bs, hbuf, wproj, cproj_b, x, out_x, nullptr,
                     C_, C_, C_, C_, 0, out_mask, nullptr, nullptr, nullptr, 8, 64);
        gsync(bar, nblk);
        ln_body(out_x, ln2w, ln2b, hbuf, NROWS);
        gsync(bar, nblk);
        for (int j = 0; j < 2; j++) {
            gemm_body<1>(As, Bs, hbuf, wfc + (size_t)j*2048*C_, fcb + j*2048,
                         nullptr, nullptr, cbuf, C_, C_, C_, 2048, 0, nullptr,
                         nullptr, nullptr, nullptr, 16, 64);
            gsync(bar, nblk);
            gemm_body<2>(As, Bs, cbuf, wfcp + (size_t)j*2048, (j == 0) ? fcpb : nullptr,
                         out_x, out_x, nullptr, 2048, 2048, 4*C_, C_, 0, nullptr,
                         nullptr, nullptr, nullptr, 8, 64);
            gsync(bar, nblk);
        }
        return;
    }

    // ---- all-pruned fast path: one-row MLP + broadcast ----
    for (int jb = blockIdx.x; jb < C_; jb += gridDim.x) {      // 1024 j-groups of 4
        int j = jb*4 + w;
        const float4* wr = (const float4*)(fcw + (size_t)j * C_);
        const float4* bb = (const float4*)ln2b;
        float s = 0.f;
        #pragma unroll
        for (int k = 0; k < 4; k++) {
            float4 av = bb[lane + 64*k];
            float4 wv = wr[lane + 64*k];
            s += av.x*wv.x + av.y*wv.y + av.z*wv.z + av.w*wv.w;
        }
        #pragma unroll
        for (int off = 32; off > 0; off >>= 1) s += __shfl_down(s, off, 64);
        if (lane == 0) {
            float v = fcb[j] + s;
            abuf[j] = 0.5f * v * (1.0f + erff(v * 0.70710678118654752f));
        }
    }
    gsync(bar, nblk);
    for (int cb = blockIdx.x; cb < C_/4; cb += gridDim.x) {    // 256 c-groups of 4
        int c = cb*4 + w;
        const float4* wr = (const float4*)(fcpw + (size_t)c * (4*C_));
        const float4* ab = (const float4*)abuf;
        float s = 0.f;
        #pragma unroll
        for (int k = 0; k < 16; k++) {
            float4 av = ab[lane + 64*k];
            float4 wv = wr[lane + 64*k];
            s += av.x*wv.x + av.y*wv.y + av.z*wv.z + av.w*wv.w;
        }
        #pragma unroll
        for (int off = 32; off > 0; off >>= 1) s += __shfl_down(s, off, 64);
        if (lane == 0) rowbuf[c] = fcpb[c] + s;
    }
    gsync(bar, nblk);
    float4 v = ((const float4*)rowbuf)[tid];
    for (int r = blockIdx.x; r < NROWS; r += gridDim.x)
        ((float4*)(out_x + (size_t)r * C_))[tid] = v;
}

extern "C" void kernel_launch(void* const* d_in, const int* in_sizes, int n_in,
                              void* d_out, int out_size, void* d_ws, size_t ws_size,
                              hipStream_t stream) {
    const float* x       = (const float*)d_in[0];
    const float* amask   = (const float*)d_in[1];
    const float* prot    = (const float*)d_in[2];
    const float* ln1w    = (const float*)d_in[3];
    const float* ln1b    = (const float*)d_in[4];
    const float* cattn_w = (const float*)d_in[5];
    const float* cattn_b = (const float*)d_in[6];
    const float* cproj_w = (const float*)d_in[7];
    const float* cproj_b = (const float*)d_in[8];
    const float* ln2w    = (const float*)d_in[9];
    const float* ln2b    = (const float*)d_in[10];
    const float* fcw     = (const float*)d_in[11];
    const float* fcb     = (const float*)d_in[12];
    const float* fcpw    = (const float*)d_in[13];
    const float* fcpb    = (const float*)d_in[14];
    const float* thr     = (const float*)d_in[15];

    unsigned short* wqkv  = (unsigned short*)d_ws;
    unsigned short* wproj = wqkv  + (size_t)3*C_*C_;
    unsigned short* wfc   = wproj + (size_t)C_*C_;
    unsigned short* wfcp  = wfc   + (size_t)4*C_*C_;
    unsigned short* hbuf  = wfcp  + (size_t)4*C_*C_;
    unsigned short* qh    = hbuf  + (size_t)NROWS*C_;
    unsigned short* kh    = qh    + (size_t)NROWS*C_;
    unsigned short* vh    = kh    + (size_t)NROWS*C_;
    unsigned short* cbuf  = qh;                        // fc chunk out (dense path)
    float* imp    = (float*)(vh + (size_t)NROWS*C_);
    int*   nsurv  = (int*)(imp + NROWS);
    float* abuf   = (float*)(nsurv + 8);
    float* rowbuf = abuf + 4*C_;
    float* linvbuf = rowbuf + C_;                      // 64*2048 fp32

    float* out_x    = (float*)d_out;
    float* out_mask = out_x + (size_t)NROWS*C_;
    float* out_loss = out_mask + NROWS;

    // prep: LN1 + qkv weight cvt + zero imp/nsurv (incl. barrier counters)
    hipLaunchKernelGGL(prep_kernel, dim3(NROWS), dim3(256), 0, stream,
                       x, ln1w, ln1b, hbuf, cattn_w, wqkv, imp, nsurv);
    // QK GEMM (N = 2048) -> qh/kh head-major (q pre-scaled by QSCALE)
    hipLaunchKernelGGL(gemm_qk_8ph, dim3(256), dim3(512), 0, stream,
                       hbuf, wqkv, cattn_b, qh, kh);
    // attention: two barrier-free streaming passes (round-4 proven-best)
    hipLaunchKernelGGL(attn_rowsum, dim3(64*32), dim3(256), 0, stream,
                       qh, kh, amask, linvbuf);
    hipLaunchKernelGGL(attn_colsum, dim3(64*32), dim3(256), 0, stream,
                       qh, kh, amask, linvbuf, imp);
    hipLaunchKernelGGL(mask_finalize, dim3(NROWS/256), dim3(256), 0, stream,
                       imp, amask, prot, thr, out_mask, out_loss, nsurv);

    // ---- consolidated tail: one plain kernel (software grid barrier) ----
    hipLaunchKernelGGL(tail_kernel, dim3(256), dim3(256), 0, stream,
                       x, amask, cproj_w, cproj_b, ln2w, ln2b, fcw, fcb,
                       fcpw, fcpb, cattn_b, wqkv, wproj, wfc, wfcp, hbuf,
                       qh, kh, vh, cbuf, out_x, out_mask, nsurv, abuf, rowbuf);
}

// Round 8
// 306.677 us; speedup vs baseline: 1.2139x; 1.2139x over previous
//
#include <hip/hip_runtime.h>
#include <math.h>

#define B_ 4
#define T_ 2048
#define C_ 1024
#define H_ 16
#define NROWS (B_*T_)   // 8192

typedef short s8v  __attribute__((ext_vector_type(8)));
typedef float f4v  __attribute__((ext_vector_type(4)));
typedef unsigned short u16v4 __attribute__((ext_vector_type(4)));

#define QSCALE 0.1803368801111f   // 0.125 * log2(e): scores in log2 domain

static __device__ __forceinline__ unsigned short f2bf(float x) {
    unsigned u = __float_as_uint(x);
    unsigned r = u + 0x7fffu + ((u >> 16) & 1u);
    return (unsigned short)(r >> 16);
}

static __device__ __forceinline__ float fexp2(float x) {
    return __builtin_amdgcn_exp2f(x);
}

static __device__ __forceinline__ void gload_lds16(const void* g, void* l) {
    __builtin_amdgcn_global_load_lds(
        (const __attribute__((address_space(1))) void*)g,
        (__attribute__((address_space(3))) void*)l, 16, 0, 0);
}

// ---- prep: LN1 row + qkv-weight cvt slice + zero imp/nsurv (grid NROWS) ----
__global__ __launch_bounds__(256) void prep_kernel(
        const float* __restrict__ x, const float* __restrict__ w,
        const float* __restrict__ b, unsigned short* __restrict__ out,
        const float* __restrict__ wsrc, unsigned short* __restrict__ wdst,
        float* __restrict__ imp, int* __restrict__ nsurv)
{
    int row = blockIdx.x;
    int tid = threadIdx.x;
    // qkv weight convert slice: 8192 blocks x 96 vec4 = 786432 = 3C*C/4
    int widx = row * 96 + tid;
    if (tid < 96) {
        float4 v = ((const float4*)wsrc)[widx];
        u16v4 o = { f2bf(v.x), f2bf(v.y), f2bf(v.z), f2bf(v.w) };
        *(u16v4*)(wdst + (size_t)widx*4) = o;
    }
    if (row < 32) imp[row*256 + tid] = 0.f;
    if (row == 32 && tid < 8) nsurv[tid] = 0;

    const float4* xr = (const float4*)(x + (size_t)row * C_);
    float4 v = xr[tid];
    float s  = v.x + v.y + v.z + v.w;
    float ss = v.x*v.x + v.y*v.y + v.z*v.z + v.w*v.w;
    #pragma unroll
    for (int off = 32; off > 0; off >>= 1) {
        s  += __shfl_down(s,  off, 64);
        ss += __shfl_down(ss, off, 64);
    }
    __shared__ float rs[4], rss[4];
    __shared__ float smu, srstd;
    int wave = tid >> 6, lane = tid & 63;
    if (lane == 0) { rs[wave] = s; rss[wave] = ss; }
    __syncthreads();
    if (tid == 0) {
        float S  = rs[0]+rs[1]+rs[2]+rs[3];
        float SS = rss[0]+rss[1]+rss[2]+rss[3];
        float mu = S * (1.0f/C_);
        float var = SS * (1.0f/C_) - mu*mu;
        smu = mu; srstd = rsqrtf(var + 1e-5f);
    }
    __syncthreads();
    float mu = smu, rstd = srstd;
    float4 wv = ((const float4*)w)[tid];
    float4 bv = ((const float4*)b)[tid];
    u16v4 o;
    o.x = f2bf((v.x-mu)*rstd*wv.x + bv.x);
    o.y = f2bf((v.y-mu)*rstd*wv.y + bv.y);
    o.z = f2bf((v.z-mu)*rstd*wv.z + bv.z);
    o.w = f2bf((v.w-mu)*rstd*wv.w + bv.w);
    *(u16v4*)(out + (size_t)row * C_ + tid*4) = o;
}

// ---- LayerNorm -> bf16 (flagged, persistent over nrows) ----
__global__ __launch_bounds__(256) void ln_bf16(const float* __restrict__ x,
        const float* __restrict__ w, const float* __restrict__ b,
        unsigned short* __restrict__ out, const int* __restrict__ flag, int nrows)
{
    if (flag && flag[0] == 0) return;
    int tid = threadIdx.x;
    __shared__ float rs[4], rss[4];
    __shared__ float smu, srstd;
    int wave = tid >> 6, lane = tid & 63;
    for (int row = blockIdx.x; row < nrows; row += gridDim.x) {
        const float4* xr = (const float4*)(x + (size_t)row * C_);
        float4 v = xr[tid];
        float s  = v.x + v.y + v.z + v.w;
        float ss = v.x*v.x + v.y*v.y + v.z*v.z + v.w*v.w;
        #pragma unroll
        for (int off = 32; off > 0; off >>= 1) {
            s  += __shfl_down(s,  off, 64);
            ss += __shfl_down(ss, off, 64);
        }
        if (lane == 0) { rs[wave] = s; rss[wave] = ss; }
        __syncthreads();
        if (tid == 0) {
            float S  = rs[0]+rs[1]+rs[2]+rs[3];
            float SS = rss[0]+rss[1]+rss[2]+rss[3];
            float mu = S * (1.0f/C_);
            float var = SS * (1.0f/C_) - mu*mu;
            smu = mu; srstd = rsqrtf(var + 1e-5f);
        }
        __syncthreads();
        float mu = smu, rstd = srstd;
        float4 wv = ((const float4*)w)[tid];
        float4 bv = ((const float4*)b)[tid];
        u16v4 o;
        o.x = f2bf((v.x-mu)*rstd*wv.x + bv.x);
        o.y = f2bf((v.y-mu)*rstd*wv.y + bv.y);
        o.z = f2bf((v.z-mu)*rstd*wv.z + bv.z);
        o.w = f2bf((v.w-mu)*rstd*wv.w + bv.w);
        *(u16v4*)(out + (size_t)row * C_ + tid*4) = o;
        __syncthreads();
    }
}

// ---- merged flagged cvt of cproj/fc/fcproj weights (persistent) ----
__global__ __launch_bounds__(256) void cvt3_bf16(
        const float* __restrict__ cprojw, const float* __restrict__ fcw,
        const float* __restrict__ fcpw,
        unsigned short* __restrict__ wproj, unsigned short* __restrict__ wfc,
        unsigned short* __restrict__ wfcp, const int* __restrict__ flag)
{
    if (flag[0] == 0) return;
    const int total = 9*C_*C_/4;
    const int n1 = C_*C_/4;
    const int n2 = n1 + C_*C_;
    for (int i = blockIdx.x * 256 + threadIdx.x; i < total; i += gridDim.x * 256) {
        const float* src; unsigned short* dst; int j;
        if (i < n1)      { src = cprojw; dst = wproj; j = i; }
        else if (i < n2) { src = fcw;    dst = wfc;   j = i - n1; }
        else             { src = fcpw;   dst = wfcp;  j = i - n2; }
        float4 v = ((const float4*)src)[j];
        u16v4 o = { f2bf(v.x), f2bf(v.y), f2bf(v.z), f2bf(v.w) };
        *(u16v4*)(dst + (size_t)j*4) = o;
    }
}

// ================= 256x256 8-phase QK GEMM (T1+T2+T3+T4+T5) =================
// M=8192 N=2048 K=1024 hard-coded. C = A (hbuf, MxK bf16) * Bw^T (NxK bf16),
// epilogue = bias + head-major q/k scatter (q pre-scaled by QSCALE).
#define STG(gbase_, ldsarr_, ah_, kt_, bb_) do { \
    gload_lds16(gbase_ + (size_t)((ah_)*128)*1024 + (kt_)*64, \
                &ldsarr_[bb_][(((ah_)*128) + (w<<3))*64]); \
    gload_lds16(gbase_ + (size_t)((ah_)*128 + 64)*1024 + (kt_)*64, \
                &ldsarr_[bb_][(((ah_)*128 + 64) + (w<<3))*64]); \
} while (0)

#define PHASE(ah_, bh_, ...) do { \
    s8v af[4][2], bf[2][2]; \
    _Pragma("unroll") \
    for (int i2 = 0; i2 < 4; i2++) { \
        int arow = ((ah_)*128 + wr*64 + i2*16 + l16)*64; \
        af[i2][0] = *(const s8v*)&As[bb][arow + (((quad)     ^ (l16&7))<<3)]; \
        af[i2][1] = *(const s8v*)&As[bb][arow + (((4 + quad) ^ (l16&7))<<3)]; \
    } \
    _Pragma("unroll") \
    for (int j2 = 0; j2 < 2; j2++) { \
        int brow = ((bh_)*128 + wc*32 + j2*16 + l16)*64; \
        bf[j2][0] = *(const s8v*)&Bs[bb][brow + (((quad)     ^ (l16&7))<<3)]; \
        bf[j2][1] = *(const s8v*)&Bs[bb][brow + (((4 + quad) ^ (l16&7))<<3)]; \
    } \
    __VA_ARGS__; \
    asm volatile("s_barrier" ::: "memory"); \
    asm volatile("s_waitcnt lgkmcnt(0)" ::: "memory"); \
    __builtin_amdgcn_sched_barrier(0); \
    __builtin_amdgcn_s_setprio(1); \
    _Pragma("unroll") \
    for (int i2 = 0; i2 < 4; i2++) \
        _Pragma("unroll") \
        for (int j2 = 0; j2 < 2; j2++) { \
            acc[(ah_)*4+i2][(bh_)*2+j2] = __builtin_amdgcn_mfma_f32_16x16x32_bf16( \
                af[i2][0], bf[j2][0], acc[(ah_)*4+i2][(bh_)*2+j2], 0, 0, 0); \
            acc[(ah_)*4+i2][(bh_)*2+j2] = __builtin_amdgcn_mfma_f32_16x16x32_bf16( \
                af[i2][1], bf[j2][1], acc[(ah_)*4+i2][(bh_)*2+j2], 0, 0, 0); \
        } \
    __builtin_amdgcn_s_setprio(0); \
    __builtin_amdgcn_sched_barrier(0); \
    asm volatile("s_barrier" ::: "memory"); \
} while (0)

__global__ __launch_bounds__(512, 2) void gemm_qk_8ph(
    const unsigned short* __restrict__ A,
    const unsigned short* __restrict__ Bw,
    const float* __restrict__ bias,
    unsigned short* __restrict__ qh, unsigned short* __restrict__ kh)
{
    __shared__ unsigned short As[2][256*64];   // 64 KiB
    __shared__ unsigned short Bs[2][256*64];   // 64 KiB

    const int tid  = threadIdx.x;
    const int w    = tid >> 6, lane = tid & 63;
    const int quad = lane >> 4, l16 = lane & 15;
    const int wr   = w >> 2, wc = w & 3;
    const int rl   = tid >> 3;                 // staging row within 64-row round
    const int kc   = (tid & 7) ^ (rl & 7);     // pre-swizzled source chunk

    // XCD-aware swizzle (T1): nwg=256, 8 XCDs, 256%8==0 -> simple bijection
    const int bid = blockIdx.x;
    const int vb  = (bid & 7) * 32 + (bid >> 3);
    const int m0  = (vb >> 3) << 8;            // 32 m-tiles
    const int n0  = (vb & 7) << 8;             // 8 n-tiles

    const unsigned short* gA0 = A  + (size_t)(m0 + rl) * 1024 + kc * 8;
    const unsigned short* gB0 = Bw + (size_t)(n0 + rl) * 1024 + kc * 8;

    // prologue: tile0 complete (oldest 8 loads), then A0/B1 of tile1
    STG(gA0, As, 0, 0, 0);
    STG(gB0, Bs, 1, 0, 0);
    STG(gA0, As, 1, 0, 0);
    STG(gB0, Bs, 0, 0, 0);
    STG(gA0, As, 0, 1, 1);
    STG(gB0, Bs, 1, 1, 1);

    f4v acc[8][4];
    #pragma unroll
    for (int i = 0; i < 8; i++)
        #pragma unroll
        for (int j = 0; j < 4; j++) {
            acc[i][j][0] = 0.f; acc[i][j][1] = 0.f;
            acc[i][j][2] = 0.f; acc[i][j][3] = 0.f;
        }

    #pragma unroll 2
    for (int t = 0; t < 16; ++t) {
        const int bb = t & 1, nb = bb ^ 1;
        if (t < 15) asm volatile("s_waitcnt vmcnt(4)" ::: "memory");
        else        asm volatile("s_waitcnt vmcnt(0)" ::: "memory");
        asm volatile("s_barrier" ::: "memory");
        __builtin_amdgcn_sched_barrier(0);
        PHASE(0, 0, if (t < 15) STG(gA0, As, 1, t+1, nb));
        PHASE(0, 1, if (t < 15) STG(gB0, Bs, 0, t+1, nb));
        PHASE(1, 1, if (t < 14) STG(gA0, As, 0, t+2, bb));
        PHASE(1, 0, if (t < 14) STG(gB0, Bs, 1, t+2, bb));
    }

    // epilogue: bias + head-major scatter (EPI3 semantics, ncoff=0, N=2048)
    #pragma unroll
    for (int j = 0; j < 4; j++) {
        int ncol = n0 + ((j >> 1) << 7) + (wc << 5) + ((j & 1) << 4) + l16;
        float bv = bias[ncol];
        int sec = ncol >> 10;
        int hh = (ncol & 1023) >> 6, dd = ncol & 63;
        unsigned short* basep = (sec == 0) ? qh : kh;
        bool qsec = (sec == 0);
        #pragma unroll
        for (int i = 0; i < 8; i++) {
            int mbase = m0 + ((i >> 2) << 7) + (wr << 6) + ((i & 3) << 4) + (quad << 2);
            #pragma unroll
            for (int reg = 0; reg < 4; reg++) {
                int m = mbase + reg;
                float v = acc[i][j][reg] + bv;
                if (qsec) v *= QSCALE;
                int b_ = m >> 11, tt = m & 2047;
                basep[(((size_t)(b_*H_ + hh))*T_ + tt)*64 + dd] = f2bf(v);
            }
        }
    }
}

// ---------------- bf16 MFMA GEMM (persistent virtual-block loop) ----------------
// EPI: 1 = bias + exact GELU -> bf16 ; 2 = bias(opt) + fp32 residual -> fp32
//      3 = bias -> bf16 head-major qkv scatter (q pre-scaled by QSCALE)
//      4 = bias + (res + v)*cm -> fp32
template<int EPI>
__global__ __launch_bounds__(256) void gemm_bf16(
    const unsigned short* __restrict__ A,
    const unsigned short* __restrict__ Bw,
    const float* __restrict__ bias,
    const float* __restrict__ res,
    float* __restrict__ Cout, unsigned short* __restrict__ Cbf,
    int K, int lda, int ldb, int ldc, int ncoff,
    const float* __restrict__ cmv,
    unsigned short* __restrict__ qh, unsigned short* __restrict__ kh,
    unsigned short* __restrict__ vh, const int* __restrict__ flag,
    int nbx, int nby)
{
    if (flag && flag[0] == 0) return;
    __shared__ unsigned short As[128*64];
    __shared__ unsigned short Bs[128*64];
    int tid = threadIdx.x;
    int w = tid >> 6, lane = tid & 63, quad = lane >> 4, l16 = lane & 15;
    int wr = w >> 1, wc = w & 1;

    int nvb = nbx * nby;
    int vb0 = blockIdx.y * gridDim.x + blockIdx.x;
    int vstride = gridDim.x * gridDim.y;

    for (int vb = vb0; vb < nvb; vb += vstride) {
        int n0 = (vb % nbx) * 128;
        int m0 = (vb / nbx) * 128;

        size_t offA[4], offB[4];
        #pragma unroll
        for (int j = 0; j < 4; j++) {
            int ci = j*256 + tid;
            int mr = ci >> 3, kcs = ci & 7;
            int kc = kcs ^ (mr & 7);
            offA[j] = (size_t)(m0 + mr) * lda + kc*8;
            offB[j] = (size_t)(n0 + mr) * ldb + kc*8;
        }

        f4v acc[4][4];
        #pragma unroll
        for (int i = 0; i < 4; i++)
            #pragma unroll
            for (int j = 0; j < 4; j++) { acc[i][j][0]=0.f; acc[i][j][1]=0.f; acc[i][j][2]=0.f; acc[i][j][3]=0.f; }

        for (int k0 = 0; k0 < K; k0 += 64) {
            __syncthreads();
            #pragma unroll
            for (int j = 0; j < 4; j++) {
                gload_lds16(A  + offA[j] + k0, &As[(j*256 + (w<<6))*8]);
                gload_lds16(Bw + offB[j] + k0, &Bs[(j*256 + (w<<6))*8]);
            }
            __syncthreads();
            #pragma unroll
            for (int c = 0; c < 2; c++) {
                s8v af[4], bf[4];
                int sw = ((c<<2) + quad) ^ (l16 & 7);
                #pragma unroll
                for (int i = 0; i < 4; i++) {
                    int mr = wr*64 + i*16 + l16;
                    af[i] = *(const s8v*)&As[mr*64 + sw*8];
                    int nr = wc*64 + i*16 + l16;
                    bf[i] = *(const s8v*)&Bs[nr*64 + sw*8];
                }
                #pragma unroll
                for (int i = 0; i < 4; i++)
                    #pragma unroll
                    for (int j = 0; j < 4; j++)
                        acc[i][j] = __builtin_amdgcn_mfma_f32_16x16x32_bf16(af[i], bf[j], acc[i][j], 0, 0, 0);
            }
        }

        #pragma unroll
        for (int j = 0; j < 4; j++) {
            int ncol = n0 + wc*64 + j*16 + l16;
            float bv = bias ? bias[ncol] : 0.f;
            int hh = 0, dd = 0;
            bool qsec = false;
            unsigned short* basep = nullptr;
            if (EPI == 3) {
                int ncolg = ncol + ncoff;
                int sec = ncolg >> 10;
                int hn = ncolg & 1023;
                hh = hn >> 6; dd = hn & 63;
                basep = (sec == 0) ? qh : (sec == 1) ? kh : vh;
                qsec = (sec == 0);
            }
            #pragma unroll
            for (int i = 0; i < 4; i++) {
                #pragma unroll
                for (int reg = 0; reg < 4; reg++) {
                    int m = m0 + wr*64 + i*16 + quad*4 + reg;
                    float v = acc[i][j][reg] + bv;
                    if (EPI == 1) {
                        v = 0.5f * v * (1.0f + erff(v * 0.70710678118654752f));
                        Cbf[(size_t)m*ldc + ncol] = f2bf(v);
                    } else if (EPI == 2) {
                        Cout[(size_t)m*ldc + ncol] = v + res[(size_t)m*ldc + ncol];
                    } else if (EPI == 3) {
                        if (qsec) v *= QSCALE;
                        int bb = m >> 11, t = m & 2047;
                        basep[(((size_t)(bb*H_ + hh))*T_ + t)*64 + dd] = f2bf(v);
                    } else if (EPI == 4) {
                        Cout[(size_t)m*ldc + ncol] = (res[(size_t)m*ldc + ncol] + v) * cmv[m];
                    }
                }
            }
        }
    }
}

// ---------------- attention pass 1: linv[bh][q] = 1/sum_k exp2(s) ----------------
// (round-4 structure) K-fragment loads register double-buffered at qt-tile
// granularity. This round: ZACC (literal-zero C operand on first MFMA of each
// chain -- deletes 64 v_mov zero-inits per tile, bit-identical) + setprio(1)
// around the MFMA cluster (T5: barrier-free multi-wave regime).
#define RS_LOADK(K_, it_) do { \
    int k0_ = (it_) * 64; \
    _Pragma("unroll") \
    for (int c_ = 0; c_ < 2; c_++) \
        _Pragma("unroll") \
        for (int nt_ = 0; nt_ < 4; nt_++) \
            K_[c_][nt_] = *(const s8v*)(kp + (size_t)(k0_ + nt_*16 + l16)*64 + c_*32 + quad*8); \
} while (0)

#define RS_COMP(K_, it_) do { \
    int k0_ = (it_) * 64; \
    float mk[4]; \
    _Pragma("unroll") \
    for (int nt_ = 0; nt_ < 4; nt_++) mk[nt_] = msk01[k0_ + nt_*16 + l16]; \
    bool allm = __all(mk[0] != 0.f && mk[1] != 0.f && mk[2] != 0.f && mk[3] != 0.f); \
    _Pragma("unroll") \
    for (int qf = 0; qf < 4; qf++) { \
        f4v acc[4]; \
        __builtin_amdgcn_s_setprio(1); \
        _Pragma("unroll") \
        for (int nt_ = 0; nt_ < 4; nt_++) { \
            acc[nt_] = __builtin_amdgcn_mfma_f32_16x16x32_bf16(aQ[qf][0], K_[0][nt_], ZACC, 0, 0, 0); \
            acc[nt_] = __builtin_amdgcn_mfma_f32_16x16x32_bf16(aQ[qf][1], K_[1][nt_], acc[nt_], 0, 0, 0); \
        } \
        __builtin_amdgcn_s_setprio(0); \
        if ((it_) < qt && allm) { \
            _Pragma("unroll") \
            for (int nt_ = 0; nt_ < 4; nt_++) \
                _Pragma("unroll") \
                for (int reg = 0; reg < 4; reg++) \
                    lrow[qf][reg] += fexp2(acc[nt_][reg]); \
        } else if ((it_) < qt) { \
            _Pragma("unroll") \
            for (int nt_ = 0; nt_ < 4; nt_++) \
                _Pragma("unroll") \
                for (int reg = 0; reg < 4; reg++) \
                    lrow[qf][reg] += fexp2(acc[nt_][reg]) * mk[nt_]; \
        } else { \
            _Pragma("unroll") \
            for (int nt_ = 0; nt_ < 4; nt_++) { \
                int kg = k0_ + nt_*16 + l16; \
                _Pragma("unroll") \
                for (int reg = 0; reg < 4; reg++) { \
                    float me = (kg <= q0 + qf*16 + quad*4 + reg) ? mk[nt_] : 0.f; \
                    lrow[qf][reg] += fexp2(acc[nt_][reg]) * me; \
                } \
            } \
        } \
    } \
} while (0)

__global__ __launch_bounds__(256) void attn_rowsum(
    const unsigned short* __restrict__ qh, const unsigned short* __restrict__ kh,
    const float* __restrict__ amask, float* __restrict__ linvbuf)
{
    __shared__ float msk01[2048];
    __shared__ float lred[4][64];

    int tid = threadIdx.x;
    int w = tid >> 6, lane = tid & 63, quad = lane >> 4, l16 = lane & 15;
    int qt = 31 - (blockIdx.x >> 6);     // heavy blocks first
    int bh = blockIdx.x & 63;
    int b  = bh >> 4;
    int q0 = qt * 64;
    int ntiles = qt + 1;

    const unsigned short* qp = qh + (size_t)bh*T_*64;
    const unsigned short* kp = kh + (size_t)bh*T_*64;
    const float* amp = amask + b*T_;

    for (int i = tid; i < ntiles*64; i += 256)
        msk01[i] = (amp[i] != 0.f) ? 1.f : 0.f;

    s8v aQ[4][2];
    #pragma unroll
    for (int qf = 0; qf < 4; qf++) {
        int row = q0 + qf*16 + l16;
        aQ[qf][0] = *(const s8v*)(qp + (size_t)row*64 + quad*8);
        aQ[qf][1] = *(const s8v*)(qp + (size_t)row*64 + 32 + quad*8);
    }

    float lrow[4][4];
    #pragma unroll
    for (int qf = 0; qf < 4; qf++)
        #pragma unroll
        for (int reg = 0; reg < 4; reg++) lrow[qf][reg] = 0.f;

    const f4v ZACC = {0.f, 0.f, 0.f, 0.f};

    s8v K0[2][4], K1[2][4];
    int it = w;
    if (it < ntiles) RS_LOADK(K0, it);
    __syncthreads();                     // msk01 ready
    if (it < ntiles) {
        while (true) {
            int itn = it + 4;
            if (itn < ntiles) {
                RS_LOADK(K1, itn);
                RS_COMP(K0, it);
                int it2 = itn + 4;
                if (it2 < ntiles) {
                    RS_LOADK(K0, it2);
                    RS_COMP(K1, itn);
                    it = it2;
                    continue;
                } else {
                    RS_COMP(K1, itn);
                    break;
                }
            } else {
                RS_COMP(K0, it);
                break;
            }
        }
    }

    #pragma unroll
    for (int qf = 0; qf < 4; qf++)
        #pragma unroll
        for (int reg = 0; reg < 4; reg++) {
            float v = lrow[qf][reg];
            v += __shfl_xor(v, 1); v += __shfl_xor(v, 2);
            v += __shfl_xor(v, 4); v += __shfl_xor(v, 8);
            lrow[qf][reg] = v;
        }
    if (l16 == 0) {
        #pragma unroll
        for (int qf = 0; qf < 4; qf++)
            #pragma unroll
            for (int reg = 0; reg < 4; reg++)
                lred[w][qf*16 + quad*4 + reg] = lrow[qf][reg];
    }
    __syncthreads();
    if (tid < 64) {
        float t = lred[0][tid] + lred[1][tid] + lred[2][tid] + lred[3][tid];
        linvbuf[(size_t)bh*T_ + q0 + tid] = (t > 0.f) ? 1.0f / t : 0.f;
    }
}

// ---------------- attention pass 2: imp[b][k] += sum_{h,q} exp2(s)*linv ----------------
// (round-4 structure) Ping-pong at FULL qt-tile granularity. This round:
// setprio(1) around the MFMA cluster (T5). VGPR kept at 128 (no ZACC here --
// colsum sits exactly at the 128-VGPR occupancy boundary).
#define CS_LOADQT(AQ_, LV_, qt_) do { \
    _Pragma("unroll") \
    for (int qf_ = 0; qf_ < 4; qf_++) { \
        int row_ = (qt_)*64 + qf_*16 + l16; \
        AQ_[qf_][0] = *(const s8v*)(qp + (size_t)row_*64 + quad*8); \
        AQ_[qf_][1] = *(const s8v*)(qp + (size_t)row_*64 + 32 + quad*8); \
        LV_[qf_] = *(const float4*)(lp + (qt_)*64 + qf_*16 + quad*4); \
    } \
} while (0)

#define CS_COMPQT(AQ_, LV_, qt_) do { \
    if ((qt_) > kc) { \
        _Pragma("unroll") \
        for (int qf_ = 0; qf_ < 4; qf_++) { \
            f4v acc[4]; \
            _Pragma("unroll") \
            for (int nt_ = 0; nt_ < 4; nt_++) { acc[nt_][0]=0.f; acc[nt_][1]=0.f; acc[nt_][2]=0.f; acc[nt_][3]=0.f; } \
            __builtin_amdgcn_s_setprio(1); \
            _Pragma("unroll") \
            for (int nt_ = 0; nt_ < 4; nt_++) { \
                acc[nt_] = __builtin_amdgcn_mfma_f32_16x16x32_bf16(AQ_[qf_][0], bk[0][nt_], acc[nt_], 0, 0, 0); \
                acc[nt_] = __builtin_amdgcn_mfma_f32_16x16x32_bf16(AQ_[qf_][1], bk[1][nt_], acc[nt_], 0, 0, 0); \
            } \
            __builtin_amdgcn_s_setprio(0); \
            float lv[4] = { LV_[qf_].x, LV_[qf_].y, LV_[qf_].z, LV_[qf_].w }; \
            _Pragma("unroll") \
            for (int nt_ = 0; nt_ < 4; nt_++) \
                _Pragma("unroll") \
                for (int reg = 0; reg < 4; reg++) \
                    cs[nt_] += fexp2(acc[nt_][reg]) * lv[reg]; \
        } \
    } else { \
        _Pragma("unroll") \
        for (int qf_ = 0; qf_ < 4; qf_++) { \
            f4v acc[4]; \
            _Pragma("unroll") \
            for (int nt_ = 0; nt_ < 4; nt_++) { acc[nt_][0]=0.f; acc[nt_][1]=0.f; acc[nt_][2]=0.f; acc[nt_][3]=0.f; } \
            __builtin_amdgcn_s_setprio(1); \
            _Pragma("unroll") \
            for (int nt_ = 0; nt_ < 4; nt_++) { \
                acc[nt_] = __builtin_amdgcn_mfma_f32_16x16x32_bf16(AQ_[qf_][0], bk[0][nt_], acc[nt_], 0, 0, 0); \
                acc[nt_] = __builtin_amdgcn_mfma_f32_16x16x32_bf16(AQ_[qf_][1], bk[1][nt_], acc[nt_], 0, 0, 0); \
            } \
            __builtin_amdgcn_s_setprio(0); \
            float lv[4] = { LV_[qf_].x, LV_[qf_].y, LV_[qf_].z, LV_[qf_].w }; \
            _Pragma("unroll") \
            for (int nt_ = 0; nt_ < 4; nt_++) { \
                int kg = k0 + nt_*16 + l16; \
                _Pragma("unroll") \
                for (int reg = 0; reg < 4; reg++) { \
                    float me = (kg <= (qt_)*64 + qf_*16 + quad*4 + reg) ? 1.f : 0.f; \
                    cs[nt_] += fexp2(acc[nt_][reg]) * lv[reg] * me; \
                } \
            } \
        } \
    } \
} while (0)

__global__ __launch_bounds__(256) void attn_colsum(
    const unsigned short* __restrict__ qh, const unsigned short* __restrict__ kh,
    const float* __restrict__ amask, const float* __restrict__ linvbuf,
    float* __restrict__ imp)
{
    __shared__ float cred[4][64];

    int tid = threadIdx.x;
    int w = tid >> 6, lane = tid & 63, quad = lane >> 4, l16 = lane & 15;
    int kc = blockIdx.x >> 6;
    int bh = blockIdx.x & 63;
    int b  = bh >> 4;
    int k0 = kc * 64;

    const unsigned short* qp = qh + (size_t)bh*T_*64;
    const unsigned short* kp = kh + (size_t)bh*T_*64;
    const float* lp = linvbuf + (size_t)bh*T_;

    s8v bk[2][4];
    float mk[4];
    #pragma unroll
    for (int nt = 0; nt < 4; nt++) {
        int key = k0 + nt*16 + l16;
        bk[0][nt] = *(const s8v*)(kp + (size_t)key*64 + quad*8);
        bk[1][nt] = *(const s8v*)(kp + (size_t)key*64 + 32 + quad*8);
        mk[nt] = amask[b*T_ + key];
    }

    float cs[4] = {0.f, 0.f, 0.f, 0.f};

    int qt = kc + w;
    if (qt < 32) {
        s8v AQa[4][2], AQb[4][2];
        float4 LVa[4], LVb[4];
        CS_LOADQT(AQa, LVa, qt);
        while (true) {
            int qtn = qt + 4;
            if (qtn < 32) {
                CS_LOADQT(AQb, LVb, qtn);
                CS_COMPQT(AQa, LVa, qt);
                int qt2 = qtn + 4;
                if (qt2 < 32) {
                    CS_LOADQT(AQa, LVa, qt2);
                    CS_COMPQT(AQb, LVb, qtn);
                    qt = qt2;
                    continue;
                } else {
                    CS_COMPQT(AQb, LVb, qtn);
                    break;
                }
            } else {
                CS_COMPQT(AQa, LVa, qt);
                break;
            }
        }
    }

    #pragma unroll
    for (int nt = 0; nt < 4; nt++) {
        float v = cs[nt] * mk[nt];
        v += __shfl_xor(v, 16);
        v += __shfl_xor(v, 32);
        if (quad == 0) cred[w][nt*16 + l16] = v;
    }
    __syncthreads();
    if (tid < 64)
        atomicAdd(&imp[b*T_ + k0 + tid],
                  cred[0][tid] + cred[1][tid] + cred[2][tid] + cred[3][tid]);
}

// ---------------- mask finalize: cm, loss, survivor count ----------------
__global__ __launch_bounds__(256) void mask_finalize(
    const float* __restrict__ imp, const float* __restrict__ amask,
    const float* __restrict__ prot, const float* __restrict__ thr,
    float* __restrict__ mask_out, float* __restrict__ loss_out,
    int* __restrict__ nsurv)
{
    int i = blockIdx.x * 256 + threadIdx.x;
    float impv = imp[i] * (1.0f / (float)(H_ * T_));
    float pm = (impv >= thr[0]) ? 1.f : 0.f;
    if (prot[i] > 0.f) pm = 1.f;
    float cm = amask[i] * pm;
    mask_out[i] = cm;
    if (i == 0) loss_out[0] = 0.f;
    unsigned long long bal = __ballot(cm != 0.f);
    int cnt = __popcll(bal);
    __shared__ int bs;
    if (threadIdx.x == 0) bs = 0;
    __syncthreads();
    if ((threadIdx.x & 63) == 0 && cnt) atomicAdd(&bs, cnt);
    __syncthreads();
    if (threadIdx.x == 0 && bs) atomicAdd(nsurv, bs);
}

// ---------------- full attention (dense fallback; persistent) ----------------
__global__ __launch_bounds__(256) void attn_full(
    const unsigned short* __restrict__ qh, const unsigned short* __restrict__ kh,
    const unsigned short* __restrict__ vh, const float* __restrict__ amask,
    unsigned short* __restrict__ y, const int* __restrict__ flag)
{
    if (flag[0] == 0) return;
    __shared__ unsigned short Ks[64][72];
    __shared__ unsigned short Vt[64][72];
    __shared__ unsigned short Ps[4][16][72];
    __shared__ float mks[64];

    int tid = threadIdx.x;
    int w = tid >> 6, lane = tid & 63, quad = lane >> 4, l16 = lane & 15;
    int nqt = T_ / 64;

    for (int vb = blockIdx.x; vb < B_*H_*nqt; vb += gridDim.x) {
        int qt = vb % nqt;
        int bh = vb / nqt;
        int b = bh >> 4, h = bh & 15;
        int q0 = qt * 64;

        const unsigned short* qp = qh + (size_t)bh * T_ * 64;
        const unsigned short* kp = kh + (size_t)bh * T_ * 64;
        const unsigned short* vp = vh + (size_t)bh * T_ * 64;

        int qrow = q0 + 16*w + l16;
        s8v aQ0 = *(const s8v*)(qp + (size_t)qrow*64 + quad*8);
        s8v aQ1 = *(const s8v*)(qp + (size_t)qrow*64 + 32 + quad*8);

        int qwmax = q0 + 16*w + 15;
        int ntiles = qt + 1;
        int qg = q0 + 16*w + quad*4;

        float lrow[4] = {0.f, 0.f, 0.f, 0.f};
        for (int it = 0; it < ntiles; ++it) {
            int k0 = it * 64;
            __syncthreads();
            for (int cid = tid; cid < 512; cid += 256) {
                int row = cid >> 3, ch = cid & 7;
                *(s8v*)&Ks[row][ch*8] = *(const s8v*)(kp + (size_t)(k0+row)*64 + ch*8);
            }
            if (tid < 64) mks[tid] = amask[b*T_ + k0 + tid];
            __syncthreads();
            if (k0 > qwmax) continue;
            f4v accS[4];
            #pragma unroll
            for (int nt = 0; nt < 4; nt++) { accS[nt][0]=0.f; accS[nt][1]=0.f; accS[nt][2]=0.f; accS[nt][3]=0.f; }
            #pragma unroll
            for (int nt = 0; nt < 4; nt++) {
                s8v b0 = *(const s8v*)&Ks[nt*16 + l16][quad*8];
                s8v b1 = *(const s8v*)&Ks[nt*16 + l16][32 + quad*8];
                accS[nt] = __builtin_amdgcn_mfma_f32_16x16x32_bf16(aQ0, b0, accS[nt], 0, 0, 0);
                accS[nt] = __builtin_amdgcn_mfma_f32_16x16x32_bf16(aQ1, b1, accS[nt], 0, 0, 0);
            }
            #pragma unroll
            for (int nt = 0; nt < 4; nt++) {
                int kg = k0 + nt*16 + l16;
                float mkv = mks[nt*16 + l16];
                #pragma unroll
                for (int reg = 0; reg < 4; reg++) {
                    bool val = (kg <= qg + reg) && (mkv != 0.f);
                    float e = fexp2(accS[nt][reg]);
                    lrow[reg] += val ? e : 0.f;
                }
            }
        }
        float linv[4];
        #pragma unroll
        for (int reg = 0; reg < 4; reg++) {
            float v = lrow[reg];
            v += __shfl_xor(v, 1); v += __shfl_xor(v, 2);
            v += __shfl_xor(v, 4); v += __shfl_xor(v, 8);
            linv[reg] = (v > 0.f) ? 1.0f / v : 0.f;
        }

        f4v accO[4];
        #pragma unroll
        for (int nt = 0; nt < 4; nt++) { accO[nt][0]=0.f; accO[nt][1]=0.f; accO[nt][2]=0.f; accO[nt][3]=0.f; }

        for (int it = 0; it < ntiles; ++it) {
            int k0 = it * 64;
            __syncthreads();
            for (int cid = tid; cid < 512; cid += 256) {
                int row = cid >> 3, ch = cid & 7;
                s8v kv = *(const s8v*)(kp + (size_t)(k0+row)*64 + ch*8);
                *(s8v*)&Ks[row][ch*8] = kv;
                s8v vv = *(const s8v*)(vp + (size_t)(k0+row)*64 + ch*8);
                #pragma unroll
                for (int j = 0; j < 8; j++) Vt[ch*8 + j][row] = (unsigned short)vv[j];
            }
            if (tid < 64) mks[tid] = amask[b*T_ + k0 + tid];
            __syncthreads();
            if (k0 > qwmax) continue;
            f4v accS[4];
            #pragma unroll
            for (int nt = 0; nt < 4; nt++) { accS[nt][0]=0.f; accS[nt][1]=0.f; accS[nt][2]=0.f; accS[nt][3]=0.f; }
            #pragma unroll
            for (int nt = 0; nt < 4; nt++) {
                s8v b0 = *(const s8v*)&Ks[nt*16 + l16][quad*8];
                s8v b1 = *(const s8v*)&Ks[nt*16 + l16][32 + quad*8];
                accS[nt] = __builtin_amdgcn_mfma_f32_16x16x32_bf16(aQ0, b0, accS[nt], 0, 0, 0);
                accS[nt] = __builtin_amdgcn_mfma_f32_16x16x32_bf16(aQ1, b1, accS[nt], 0, 0, 0);
            }
            #pragma unroll
            for (int nt = 0; nt < 4; nt++) {
                int kg = k0 + nt*16 + l16;
                float mkv = mks[nt*16 + l16];
                #pragma unroll
                for (int reg = 0; reg < 4; reg++) {
                    bool val = (kg <= qg + reg) && (mkv != 0.f);
                    float p = val ? fexp2(accS[nt][reg]) * linv[reg] : 0.f;
                    Ps[w][quad*4 + reg][nt*16 + l16] = f2bf(p);
                }
            }
            s8v aP0 = *(const s8v*)&Ps[w][l16][quad*8];
            s8v aP1 = *(const s8v*)&Ps[w][l16][32 + quad*8];
            #pragma unroll
            for (int nt = 0; nt < 4; nt++) {
                s8v bv0 = *(const s8v*)&Vt[nt*16 + l16][quad*8];
                s8v bv1 = *(const s8v*)&Vt[nt*16 + l16][32 + quad*8];
                accO[nt] = __builtin_amdgcn_mfma_f32_16x16x32_bf16(aP0, bv0, accO[nt], 0, 0, 0);
                accO[nt] = __builtin_amdgcn_mfma_f32_16x16x32_bf16(aP1, bv1, accO[nt], 0, 0, 0);
            }
        }
        #pragma unroll
        for (int nt = 0; nt < 4; nt++) {
            #pragma unroll
            for (int reg = 0; reg < 4; reg++) {
                int q = q0 + 16*w + quad*4 + reg;
                y[((size_t)(b*T_ + q))*C_ + h*64 + nt*16 + l16] = f2bf(accO[nt][reg]);
            }
        }
        __syncthreads();
    }
}

// ---------------- all-pruned fast path: one-row MLP + broadcast ----------------
__global__ __launch_bounds__(256) void ap_fc(const int* __restrict__ nsurv,
        const float* __restrict__ ln2b, const float* __restrict__ fcw,
        const float* __restrict__ fcb, float* __restrict__ abuf)
{
    if (nsurv[0] != 0) return;
    int j = blockIdx.x * 4 + (threadIdx.x >> 6);
    int lane = threadIdx.x & 63;
    const float4* wr = (const float4*)(fcw + (size_t)j * C_);
    const float4* bb = (const float4*)ln2b;
    float s = 0.f;
    #pragma unroll
    for (int k = 0; k < 4; k++) {
        float4 a = bb[lane + 64*k];
        float4 wv = wr[lane + 64*k];
        s += a.x*wv.x + a.y*wv.y + a.z*wv.z + a.w*wv.w;
    }
    #pragma unroll
    for (int off = 32; off > 0; off >>= 1) s += __shfl_down(s, off, 64);
    if (lane == 0) {
        float v = fcb[j] + s;
        abuf[j] = 0.5f * v * (1.0f + erff(v * 0.70710678118654752f));
    }
}

__global__ __launch_bounds__(256) void ap_fcp(const int* __restrict__ nsurv,
        const float* __restrict__ abuf, const float* __restrict__ fcpw,
        const float* __restrict__ fcpb, float* __restrict__ rowbuf)
{
    if (nsurv[0] != 0) return;
    int c = blockIdx.x * 4 + (threadIdx.x >> 6);
    int lane = threadIdx.x & 63;
    const float4* wr = (const float4*)(fcpw + (size_t)c * (4*C_));
    const float4* ab = (const float4*)abuf;
    float s = 0.f;
    #pragma unroll
    for (int k = 0; k < 16; k++) {
        float4 a = ab[lane + 64*k];
        float4 wv = wr[lane + 64*k];
        s += a.x*wv.x + a.y*wv.y + a.z*wv.z + a.w*wv.w;
    }
    #pragma unroll
    for (int off = 32; off > 0; off >>= 1) s += __shfl_down(s, off, 64);
    if (lane == 0) rowbuf[c] = fcpb[c] + s;
}

__global__ __launch_bounds__(256) void ap_bcast(const int* __restrict__ nsurv,
        const float* __restrict__ rowbuf, float* __restrict__ out_x)
{
    if (nsurv[0] != 0) return;
    float4 v = ((const float4*)rowbuf)[threadIdx.x];
    for (int r = blockIdx.x; r < NROWS; r += gridDim.x)
        ((float4*)(out_x + (size_t)r * C_))[threadIdx.x] = v;
}

extern "C" void kernel_launch(void* const* d_in, const int* in_sizes, int n_in,
                              void* d_out, int out_size, void* d_ws, size_t ws_size,
                              hipStream_t stream) {
    const float* x       = (const float*)d_in[0];
    const float* amask   = (const float*)d_in[1];
    const float* prot    = (const float*)d_in[2];
    const float* ln1w    = (const float*)d_in[3];
    const float* ln1b    = (const float*)d_in[4];
    const float* cattn_w = (const float*)d_in[5];
    const float* cattn_b = (const float*)d_in[6];
    const float* cproj_w = (const float*)d_in[7];
    const float* cproj_b = (const float*)d_in[8];
    const float* ln2w    = (const float*)d_in[9];
    const float* ln2b    = (const float*)d_in[10];
    const float* fcw     = (const float*)d_in[11];
    const float* fcb     = (const float*)d_in[12];
    const float* fcpw    = (const float*)d_in[13];
    const float* fcpb    = (const float*)d_in[14];
    const float* thr     = (const float*)d_in[15];

    unsigned short* wqkv  = (unsigned short*)d_ws;
    unsigned short* wproj = wqkv  + (size_t)3*C_*C_;
    unsigned short* wfc   = wproj + (size_t)C_*C_;
    unsigned short* wfcp  = wfc   + (size_t)4*C_*C_;
    unsigned short* hbuf  = wfcp  + (size_t)4*C_*C_;
    unsigned short* qh    = hbuf  + (size_t)NROWS*C_;
    unsigned short* kh    = qh    + (size_t)NROWS*C_;
    unsigned short* vh    = kh    + (size_t)NROWS*C_;
    unsigned short* cbuf  = qh;                        // fc chunk out (dense path)
    float* imp    = (float*)(vh + (size_t)NROWS*C_);
    int*   nsurv  = (int*)(imp + NROWS);
    float* abuf   = (float*)(nsurv + 8);
    float* rowbuf = abuf + 4*C_;
    float* linvbuf = rowbuf + C_;                      // 64*2048 fp32

    float* out_x    = (float*)d_out;
    float* out_mask = out_x + (size_t)NROWS*C_;
    float* out_loss = out_mask + NROWS;

    // prep: LN1 + qkv weight cvt + zero imp/nsurv
    hipLaunchKernelGGL(prep_kernel, dim3(NROWS), dim3(256), 0, stream,
                       x, ln1w, ln1b, hbuf, cattn_w, wqkv, imp, nsurv);
    // QK GEMM (N = 2048) -> qh/kh head-major (q pre-scaled by QSCALE)
    hipLaunchKernelGGL(gemm_qk_8ph, dim3(256), dim3(512), 0, stream,
                       hbuf, wqkv, cattn_b, qh, kh);
    // attention: two barrier-free streaming passes (round-4 + ZACC/setprio)
    hipLaunchKernelGGL(attn_rowsum, dim3(64*32), dim3(256), 0, stream,
                       qh, kh, amask, linvbuf);
    hipLaunchKernelGGL(attn_colsum, dim3(64*32), dim3(256), 0, stream,
                       qh, kh, amask, linvbuf, imp);
    hipLaunchKernelGGL(mask_finalize, dim3(NROWS/256), dim3(256), 0, stream,
                       imp, amask, prot, thr, out_mask, out_loss, nsurv);

    // ---- dense fallback path (persistent grids; early-exit when nsurv == 0) ----
    hipLaunchKernelGGL(cvt3_bf16, dim3(512), dim3(256), 0, stream,
                       cproj_w, fcw, fcpw, wproj, wfc, wfcp, nsurv);
    hipLaunchKernelGGL((gemm_bf16<3>), dim3(512), dim3(256), 0, stream,
                       hbuf, wqkv + (size_t)2048*C_, cattn_b + 2048, nullptr, nullptr, nullptr,
                       C_, C_, C_, 0, 2048, nullptr, qh, kh, vh, nsurv, 8, 64);
    hipLaunchKernelGGL(attn_full, dim3(512), dim3(256), 0, stream,
                       qh, kh, vh, amask, hbuf, nsurv);
    hipLaunchKernelGGL((gemm_bf16<4>), dim3(512), dim3(256), 0, stream,
                       hbuf, wproj, cproj_b, x, out_x, nullptr,
                       C_, C_, C_, C_, 0, out_mask, nullptr, nullptr, nullptr, nsurv, 8, 64);
    hipLaunchKernelGGL(ln_bf16, dim3(512), dim3(256), 0, stream,
                       out_x, ln2w, ln2b, hbuf, nsurv, NROWS);
    for (int j = 0; j < 2; j++) {
        hipLaunchKernelGGL((gemm_bf16<1>), dim3(512), dim3(256), 0, stream,
                           hbuf, wfc + (size_t)j*2048*C_, fcb + j*2048, nullptr, nullptr, cbuf,
                           C_, C_, C_, 2048, 0, nullptr, nullptr, nullptr, nullptr, nsurv, 16, 64);
        hipLaunchKernelGGL((gemm_bf16<2>), dim3(512), dim3(256), 0, stream,
                           cbuf, wfcp + (size_t)j*2048, (j == 0) ? fcpb : nullptr, out_x, out_x, nullptr,
                           2048, 2048, 4*C_, C_, 0, nullptr, nullptr, nullptr, nullptr, nsurv, 8, 64);
    }

    // ---- all-pruned fast path (early-exit when nsurv != 0) ----
    hipLaunchKernelGGL(ap_fc,    dim3(4*C_/4), dim3(256), 0, stream, nsurv, ln2b, fcw, fcb, abuf);
    hipLaunchKernelGGL(ap_fcp,   dim3(C_/4),   dim3(256), 0, stream, nsurv, abuf, fcpw, fcpb, rowbuf);
    hipLaunchKernelGGL(ap_bcast, dim3(512),    dim3(256), 0, stream, nsurv, rowbuf, out_x);
}

// Round 9
// 293.453 us; speedup vs baseline: 1.2686x; 1.0451x over previous
//
#include <hip/hip_runtime.h>
#include <math.h>

#define B_ 4
#define T_ 2048
#define C_ 1024
#define H_ 16
#define NROWS (B_*T_)   // 8192

typedef short s8v  __attribute__((ext_vector_type(8)));
typedef float f4v  __attribute__((ext_vector_type(4)));
typedef unsigned short u16v4 __attribute__((ext_vector_type(4)));

#define QSCALE 0.1803368801111f   // 0.125 * log2(e): scores in log2 domain

static __device__ __forceinline__ unsigned short f2bf(float x) {
    unsigned u = __float_as_uint(x);
    unsigned r = u + 0x7fffu + ((u >> 16) & 1u);
    return (unsigned short)(r >> 16);
}

static __device__ __forceinline__ float fexp2(float x) {
    return __builtin_amdgcn_exp2f(x);
}

static __device__ __forceinline__ void gload_lds16(const void* g, void* l) {
    __builtin_amdgcn_global_load_lds(
        (const __attribute__((address_space(1))) void*)g,
        (__attribute__((address_space(3))) void*)l, 16, 0, 0);
}

// ---- software grid barrier (dense path only; all blocks co-resident) ----
// bar[0]=arrival counter, bar[1]=generation; zeroed by prep_kernel each iter.
static __device__ __forceinline__ void gsync(int* bar, int nblk) {
    __syncthreads();
    __threadfence();
    if (threadIdx.x == 0) {
        int* cnt = bar;
        int* gen = bar + 1;
        int g = __hip_atomic_load(gen, __ATOMIC_ACQUIRE, __HIP_MEMORY_SCOPE_AGENT);
        int a = __hip_atomic_fetch_add(cnt, 1, __ATOMIC_ACQ_REL, __HIP_MEMORY_SCOPE_AGENT);
        if (a == nblk - 1) {
            __hip_atomic_store(cnt, 0, __ATOMIC_RELAXED, __HIP_MEMORY_SCOPE_AGENT);
            __hip_atomic_fetch_add(gen, 1, __ATOMIC_ACQ_REL, __HIP_MEMORY_SCOPE_AGENT);
        } else {
            while (__hip_atomic_load(gen, __ATOMIC_ACQUIRE, __HIP_MEMORY_SCOPE_AGENT) == g)
                __builtin_amdgcn_s_sleep(2);
        }
    }
    __syncthreads();
}

// ---- prep: LN1 row + qkv-weight cvt slice + zero imp/nsurv (grid NROWS) ----
__global__ __launch_bounds__(256) void prep_kernel(
        const float* __restrict__ x, const float* __restrict__ w,
        const float* __restrict__ b, unsigned short* __restrict__ out,
        const float* __restrict__ wsrc, unsigned short* __restrict__ wdst,
        float* __restrict__ imp, int* __restrict__ nsurv)
{
    int row = blockIdx.x;
    int tid = threadIdx.x;
    // qkv weight convert slice: 8192 blocks x 96 vec4 = 786432 = 3C*C/4
    int widx = row * 96 + tid;
    if (tid < 96) {
        float4 v = ((const float4*)wsrc)[widx];
        u16v4 o = { f2bf(v.x), f2bf(v.y), f2bf(v.z), f2bf(v.w) };
        *(u16v4*)(wdst + (size_t)widx*4) = o;
    }
    if (row < 32) imp[row*256 + tid] = 0.f;
    if (row == 32 && tid < 8) nsurv[tid] = 0;

    const float4* xr = (const float4*)(x + (size_t)row * C_);
    float4 v = xr[tid];
    float s  = v.x + v.y + v.z + v.w;
    float ss = v.x*v.x + v.y*v.y + v.z*v.z + v.w*v.w;
    #pragma unroll
    for (int off = 32; off > 0; off >>= 1) {
        s  += __shfl_down(s,  off, 64);
        ss += __shfl_down(ss, off, 64);
    }
    __shared__ float rs[4], rss[4];
    __shared__ float smu, srstd;
    int wave = tid >> 6, lane = tid & 63;
    if (lane == 0) { rs[wave] = s; rss[wave] = ss; }
    __syncthreads();
    if (tid == 0) {
        float S  = rs[0]+rs[1]+rs[2]+rs[3];
        float SS = rss[0]+rss[1]+rss[2]+rss[3];
        float mu = S * (1.0f/C_);
        float var = SS * (1.0f/C_) - mu*mu;
        smu = mu; srstd = rsqrtf(var + 1e-5f);
    }
    __syncthreads();
    float mu = smu, rstd = srstd;
    float4 wv = ((const float4*)w)[tid];
    float4 bv = ((const float4*)b)[tid];
    u16v4 o;
    o.x = f2bf((v.x-mu)*rstd*wv.x + bv.x);
    o.y = f2bf((v.y-mu)*rstd*wv.y + bv.y);
    o.z = f2bf((v.z-mu)*rstd*wv.z + bv.z);
    o.w = f2bf((v.w-mu)*rstd*wv.w + bv.w);
    *(u16v4*)(out + (size_t)row * C_ + tid*4) = o;
}

// ================= 256x256 8-phase QK GEMM (T1+T2+T3+T4+T5) =================
// M=8192 N=2048 K=1024 hard-coded. C = A (hbuf, MxK bf16) * Bw^T (NxK bf16),
// epilogue = bias + head-major q/k scatter (q pre-scaled by QSCALE).
#define STG(gbase_, ldsarr_, ah_, kt_, bb_) do { \
    gload_lds16(gbase_ + (size_t)((ah_)*128)*1024 + (kt_)*64, \
                &ldsarr_[bb_][(((ah_)*128) + (w<<3))*64]); \
    gload_lds16(gbase_ + (size_t)((ah_)*128 + 64)*1024 + (kt_)*64, \
                &ldsarr_[bb_][(((ah_)*128 + 64) + (w<<3))*64]); \
} while (0)

#define PHASE(ah_, bh_, ...) do { \
    s8v af[4][2], bf[2][2]; \
    _Pragma("unroll") \
    for (int i2 = 0; i2 < 4; i2++) { \
        int arow = ((ah_)*128 + wr*64 + i2*16 + l16)*64; \
        af[i2][0] = *(const s8v*)&As[bb][arow + (((quad)     ^ (l16&7))<<3)]; \
        af[i2][1] = *(const s8v*)&As[bb][arow + (((4 + quad) ^ (l16&7))<<3)]; \
    } \
    _Pragma("unroll") \
    for (int j2 = 0; j2 < 2; j2++) { \
        int brow = ((bh_)*128 + wc*32 + j2*16 + l16)*64; \
        bf[j2][0] = *(const s8v*)&Bs[bb][brow + (((quad)     ^ (l16&7))<<3)]; \
        bf[j2][1] = *(const s8v*)&Bs[bb][brow + (((4 + quad) ^ (l16&7))<<3)]; \
    } \
    __VA_ARGS__; \
    asm volatile("s_barrier" ::: "memory"); \
    asm volatile("s_waitcnt lgkmcnt(0)" ::: "memory"); \
    __builtin_amdgcn_sched_barrier(0); \
    __builtin_amdgcn_s_setprio(1); \
    _Pragma("unroll") \
    for (int i2 = 0; i2 < 4; i2++) \
        _Pragma("unroll") \
        for (int j2 = 0; j2 < 2; j2++) { \
            acc[(ah_)*4+i2][(bh_)*2+j2] = __builtin_amdgcn_mfma_f32_16x16x32_bf16( \
                af[i2][0], bf[j2][0], acc[(ah_)*4+i2][(bh_)*2+j2], 0, 0, 0); \
            acc[(ah_)*4+i2][(bh_)*2+j2] = __builtin_amdgcn_mfma_f32_16x16x32_bf16( \
                af[i2][1], bf[j2][1], acc[(ah_)*4+i2][(bh_)*2+j2], 0, 0, 0); \
        } \
    __builtin_amdgcn_s_setprio(0); \
    __builtin_amdgcn_sched_barrier(0); \
    asm volatile("s_barrier" ::: "memory"); \
} while (0)

__global__ __launch_bounds__(512, 2) void gemm_qk_8ph(
    const unsigned short* __restrict__ A,
    const unsigned short* __restrict__ Bw,
    const float* __restrict__ bias,
    unsigned short* __restrict__ qh, unsigned short* __restrict__ kh)
{
    __shared__ unsigned short As[2][256*64];   // 64 KiB
    __shared__ unsigned short Bs[2][256*64];   // 64 KiB

    const int tid  = threadIdx.x;
    const int w    = tid >> 6, lane = tid & 63;
    const int quad = lane >> 4, l16 = lane & 15;
    const int wr   = w >> 2, wc = w & 3;
    const int rl   = tid >> 3;                 // staging row within 64-row round
    const int kc   = (tid & 7) ^ (rl & 7);     // pre-swizzled source chunk

    // XCD-aware swizzle (T1): nwg=256, 8 XCDs, 256%8==0 -> simple bijection
    const int bid = blockIdx.x;
    const int vb  = (bid & 7) * 32 + (bid >> 3);
    const int m0  = (vb >> 3) << 8;            // 32 m-tiles
    const int n0  = (vb & 7) << 8;             // 8 n-tiles

    const unsigned short* gA0 = A  + (size_t)(m0 + rl) * 1024 + kc * 8;
    const unsigned short* gB0 = Bw + (size_t)(n0 + rl) * 1024 + kc * 8;

    // prologue: tile0 complete (oldest 8 loads), then A0/B1 of tile1
    STG(gA0, As, 0, 0, 0);
    STG(gB0, Bs, 1, 0, 0);
    STG(gA0, As, 1, 0, 0);
    STG(gB0, Bs, 0, 0, 0);
    STG(gA0, As, 0, 1, 1);
    STG(gB0, Bs, 1, 1, 1);

    f4v acc[8][4];
    #pragma unroll
    for (int i = 0; i < 8; i++)
        #pragma unroll
        for (int j = 0; j < 4; j++) {
            acc[i][j][0] = 0.f; acc[i][j][1] = 0.f;
            acc[i][j][2] = 0.f; acc[i][j][3] = 0.f;
        }

    #pragma unroll 2
    for (int t = 0; t < 16; ++t) {
        const int bb = t & 1, nb = bb ^ 1;
        if (t < 15) asm volatile("s_waitcnt vmcnt(4)" ::: "memory");
        else        asm volatile("s_waitcnt vmcnt(0)" ::: "memory");
        asm volatile("s_barrier" ::: "memory");
        __builtin_amdgcn_sched_barrier(0);
        PHASE(0, 0, if (t < 15) STG(gA0, As, 1, t+1, nb));
        PHASE(0, 1, if (t < 15) STG(gB0, Bs, 0, t+1, nb));
        PHASE(1, 1, if (t < 14) STG(gA0, As, 0, t+2, bb));
        PHASE(1, 0, if (t < 14) STG(gB0, Bs, 1, t+2, bb));
    }

    // epilogue: bias + head-major scatter (EPI3 semantics, ncoff=0, N=2048)
    #pragma unroll
    for (int j = 0; j < 4; j++) {
        int ncol = n0 + ((j >> 1) << 7) + (wc << 5) + ((j & 1) << 4) + l16;
        float bv = bias[ncol];
        int sec = ncol >> 10;
        int hh = (ncol & 1023) >> 6, dd = ncol & 63;
        unsigned short* basep = (sec == 0) ? qh : kh;
        bool qsec = (sec == 0);
        #pragma unroll
        for (int i = 0; i < 8; i++) {
            int mbase = m0 + ((i >> 2) << 7) + (wr << 6) + ((i & 3) << 4) + (quad << 2);
            #pragma unroll
            for (int reg = 0; reg < 4; reg++) {
                int m = mbase + reg;
                float v = acc[i][j][reg] + bv;
                if (qsec) v *= QSCALE;
                int b_ = m >> 11, tt = m & 2047;
                basep[(((size_t)(b_*H_ + hh))*T_ + tt)*64 + dd] = f2bf(v);
            }
        }
    }
}

// ---------------- attention pass 1: linv[bh][q] = 1/sum_k exp2(s) ----------------
// (round-4 proven-best) K-fragment loads register double-buffered at qt-tile
// granularity: loads for tile it+4 issue BEFORE compute of tile it
// (32 MFMA + 64 exp2 ~ 700+ cyc), hiding the L2/L3 load latency.
#define RS_LOADK(K_, it_) do { \
    int k0_ = (it_) * 64; \
    _Pragma("unroll") \
    for (int c_ = 0; c_ < 2; c_++) \
        _Pragma("unroll") \
        for (int nt_ = 0; nt_ < 4; nt_++) \
            K_[c_][nt_] = *(const s8v*)(kp + (size_t)(k0_ + nt_*16 + l16)*64 + c_*32 + quad*8); \
} while (0)

#define RS_COMP(K_, it_) do { \
    int k0_ = (it_) * 64; \
    float mk[4]; \
    _Pragma("unroll") \
    for (int nt_ = 0; nt_ < 4; nt_++) mk[nt_] = msk01[k0_ + nt_*16 + l16]; \
    bool allm = __all(mk[0] != 0.f && mk[1] != 0.f && mk[2] != 0.f && mk[3] != 0.f); \
    _Pragma("unroll") \
    for (int qf = 0; qf < 4; qf++) { \
        f4v acc[4]; \
        _Pragma("unroll") \
        for (int nt_ = 0; nt_ < 4; nt_++) { acc[nt_][0]=0.f; acc[nt_][1]=0.f; acc[nt_][2]=0.f; acc[nt_][3]=0.f; } \
        _Pragma("unroll") \
        for (int c_ = 0; c_ < 2; c_++) \
            _Pragma("unroll") \
            for (int nt_ = 0; nt_ < 4; nt_++) \
                acc[nt_] = __builtin_amdgcn_mfma_f32_16x16x32_bf16(aQ[qf][c_], K_[c_][nt_], acc[nt_], 0, 0, 0); \
        if ((it_) < qt && allm) { \
            _Pragma("unroll") \
            for (int nt_ = 0; nt_ < 4; nt_++) \
                _Pragma("unroll") \
                for (int reg = 0; reg < 4; reg++) \
                    lrow[qf][reg] += fexp2(acc[nt_][reg]); \
        } else if ((it_) < qt) { \
            _Pragma("unroll") \
            for (int nt_ = 0; nt_ < 4; nt_++) \
                _Pragma("unroll") \
                for (int reg = 0; reg < 4; reg++) \
                    lrow[qf][reg] += fexp2(acc[nt_][reg]) * mk[nt_]; \
        } else { \
            _Pragma("unroll") \
            for (int nt_ = 0; nt_ < 4; nt_++) { \
                int kg = k0_ + nt_*16 + l16; \
                _Pragma("unroll") \
                for (int reg = 0; reg < 4; reg++) { \
                    float me = (kg <= q0 + qf*16 + quad*4 + reg) ? mk[nt_] : 0.f; \
                    lrow[qf][reg] += fexp2(acc[nt_][reg]) * me; \
                } \
            } \
        } \
    } \
} while (0)

__global__ __launch_bounds__(256) void attn_rowsum(
    const unsigned short* __restrict__ qh, const unsigned short* __restrict__ kh,
    const float* __restrict__ amask, float* __restrict__ linvbuf)
{
    __shared__ float msk01[2048];
    __shared__ float lred[4][64];

    int tid = threadIdx.x;
    int w = tid >> 6, lane = tid & 63, quad = lane >> 4, l16 = lane & 15;
    int qt = 31 - (blockIdx.x >> 6);     // heavy blocks first
    int bh = blockIdx.x & 63;
    int b  = bh >> 4;
    int q0 = qt * 64;
    int ntiles = qt + 1;

    const unsigned short* qp = qh + (size_t)bh*T_*64;
    const unsigned short* kp = kh + (size_t)bh*T_*64;
    const float* amp = amask + b*T_;

    for (int i = tid; i < ntiles*64; i += 256)
        msk01[i] = (amp[i] != 0.f) ? 1.f : 0.f;

    s8v aQ[4][2];
    #pragma unroll
    for (int qf = 0; qf < 4; qf++) {
        int row = q0 + qf*16 + l16;
        aQ[qf][0] = *(const s8v*)(qp + (size_t)row*64 + quad*8);
        aQ[qf][1] = *(const s8v*)(qp + (size_t)row*64 + 32 + quad*8);
    }

    float lrow[4][4];
    #pragma unroll
    for (int qf = 0; qf < 4; qf++)
        #pragma unroll
        for (int reg = 0; reg < 4; reg++) lrow[qf][reg] = 0.f;

    s8v K0[2][4], K1[2][4];
    int it = w;
    if (it < ntiles) RS_LOADK(K0, it);
    __syncthreads();                     // msk01 ready
    if (it < ntiles) {
        while (true) {
            int itn = it + 4;
            if (itn < ntiles) {
                RS_LOADK(K1, itn);
                RS_COMP(K0, it);
                int it2 = itn + 4;
                if (it2 < ntiles) {
                    RS_LOADK(K0, it2);
                    RS_COMP(K1, itn);
                    it = it2;
                    continue;
                } else {
                    RS_COMP(K1, itn);
                    break;
                }
            } else {
                RS_COMP(K0, it);
                break;
            }
        }
    }

    #pragma unroll
    for (int qf = 0; qf < 4; qf++)
        #pragma unroll
        for (int reg = 0; reg < 4; reg++) {
            float v = lrow[qf][reg];
            v += __shfl_xor(v, 1); v += __shfl_xor(v, 2);
            v += __shfl_xor(v, 4); v += __shfl_xor(v, 8);
            lrow[qf][reg] = v;
        }
    if (l16 == 0) {
        #pragma unroll
        for (int qf = 0; qf < 4; qf++)
            #pragma unroll
            for (int reg = 0; reg < 4; reg++)
                lred[w][qf*16 + quad*4 + reg] = lrow[qf][reg];
    }
    __syncthreads();
    if (tid < 64) {
        float t = lred[0][tid] + lred[1][tid] + lred[2][tid] + lred[3][tid];
        linvbuf[(size_t)bh*T_ + q0 + tid] = (t > 0.f) ? 1.0f / t : 0.f;
    }
}

// ---------------- attention pass 2: imp[b][k] += sum_{h,q} exp2(s)*linv ----------------
// (round-4 proven-best) Ping-pong at FULL qt-tile granularity: stage all 4 qf
// Q-fragments + 4 linv4 for tile qt+4 before computing tile qt's 32 MFMA +
// 64 exp2 -- the big compute stage hides the L2/L3 latency.
#define CS_LOADQT(AQ_, LV_, qt_) do { \
    _Pragma("unroll") \
    for (int qf_ = 0; qf_ < 4; qf_++) { \
        int row_ = (qt_)*64 + qf_*16 + l16; \
        AQ_[qf_][0] = *(const s8v*)(qp + (size_t)row_*64 + quad*8); \
        AQ_[qf_][1] = *(const s8v*)(qp + (size_t)row_*64 + 32 + quad*8); \
        LV_[qf_] = *(const float4*)(lp + (qt_)*64 + qf_*16 + quad*4); \
    } \
} while (0)

#define CS_COMPQT(AQ_, LV_, qt_) do { \
    if ((qt_) > kc) { \
        _Pragma("unroll") \
        for (int qf_ = 0; qf_ < 4; qf_++) { \
            f4v acc[4]; \
            _Pragma("unroll") \
            for (int nt_ = 0; nt_ < 4; nt_++) { acc[nt_][0]=0.f; acc[nt_][1]=0.f; acc[nt_][2]=0.f; acc[nt_][3]=0.f; } \
            _Pragma("unroll") \
            for (int nt_ = 0; nt_ < 4; nt_++) { \
                acc[nt_] = __builtin_amdgcn_mfma_f32_16x16x32_bf16(AQ_[qf_][0], bk[0][nt_], acc[nt_], 0, 0, 0); \
                acc[nt_] = __builtin_amdgcn_mfma_f32_16x16x32_bf16(AQ_[qf_][1], bk[1][nt_], acc[nt_], 0, 0, 0); \
            } \
            float lv[4] = { LV_[qf_].x, LV_[qf_].y, LV_[qf_].z, LV_[qf_].w }; \
            _Pragma("unroll") \
            for (int nt_ = 0; nt_ < 4; nt_++) \
                _Pragma("unroll") \
                for (int reg = 0; reg < 4; reg++) \
                    cs[nt_] += fexp2(acc[nt_][reg]) * lv[reg]; \
        } \
    } else { \
        _Pragma("unroll") \
        for (int qf_ = 0; qf_ < 4; qf_++) { \
            f4v acc[4]; \
            _Pragma("unroll") \
            for (int nt_ = 0; nt_ < 4; nt_++) { acc[nt_][0]=0.f; acc[nt_][1]=0.f; acc[nt_][2]=0.f; acc[nt_][3]=0.f; } \
            _Pragma("unroll") \
            for (int nt_ = 0; nt_ < 4; nt_++) { \
                acc[nt_] = __builtin_amdgcn_mfma_f32_16x16x32_bf16(AQ_[qf_][0], bk[0][nt_], acc[nt_], 0, 0, 0); \
                acc[nt_] = __builtin_amdgcn_mfma_f32_16x16x32_bf16(AQ_[qf_][1], bk[1][nt_], acc[nt_], 0, 0, 0); \
            } \
            float lv[4] = { LV_[qf_].x, LV_[qf_].y, LV_[qf_].z, LV_[qf_].w }; \
            _Pragma("unroll") \
            for (int nt_ = 0; nt_ < 4; nt_++) { \
                int kg = k0 + nt_*16 + l16; \
                _Pragma("unroll") \
                for (int reg = 0; reg < 4; reg++) { \
                    float me = (kg <= (qt_)*64 + qf_*16 + quad*4 + reg) ? 1.f : 0.f; \
                    cs[nt_] += fexp2(acc[nt_][reg]) * lv[reg] * me; \
                } \
            } \
        } \
    } \
} while (0)

__global__ __launch_bounds__(256) void attn_colsum(
    const unsigned short* __restrict__ qh, const unsigned short* __restrict__ kh,
    const float* __restrict__ amask, const float* __restrict__ linvbuf,
    float* __restrict__ imp)
{
    __shared__ float cred[4][64];

    int tid = threadIdx.x;
    int w = tid >> 6, lane = tid & 63, quad = lane >> 4, l16 = lane & 15;
    int kc = blockIdx.x >> 6;
    int bh = blockIdx.x & 63;
    int b  = bh >> 4;
    int k0 = kc * 64;

    const unsigned short* qp = qh + (size_t)bh*T_*64;
    const unsigned short* kp = kh + (size_t)bh*T_*64;
    const float* lp = linvbuf + (size_t)bh*T_;

    s8v bk[2][4];
    float mk[4];
    #pragma unroll
    for (int nt = 0; nt < 4; nt++) {
        int key = k0 + nt*16 + l16;
        bk[0][nt] = *(const s8v*)(kp + (size_t)key*64 + quad*8);
        bk[1][nt] = *(const s8v*)(kp + (size_t)key*64 + 32 + quad*8);
        mk[nt] = amask[b*T_ + key];
    }

    float cs[4] = {0.f, 0.f, 0.f, 0.f};

    int qt = kc + w;
    if (qt < 32) {
        s8v AQa[4][2], AQb[4][2];
        float4 LVa[4], LVb[4];
        CS_LOADQT(AQa, LVa, qt);
        while (true) {
            int qtn = qt + 4;
            if (qtn < 32) {
                CS_LOADQT(AQb, LVb, qtn);
                CS_COMPQT(AQa, LVa, qt);
                int qt2 = qtn + 4;
                if (qt2 < 32) {
                    CS_LOADQT(AQa, LVa, qt2);
                    CS_COMPQT(AQb, LVb, qtn);
                    qt = qt2;
                    continue;
                } else {
                    CS_COMPQT(AQb, LVb, qtn);
                    break;
                }
            } else {
                CS_COMPQT(AQa, LVa, qt);
                break;
            }
        }
    }

    #pragma unroll
    for (int nt = 0; nt < 4; nt++) {
        float v = cs[nt] * mk[nt];
        v += __shfl_xor(v, 16);
        v += __shfl_xor(v, 32);
        if (quad == 0) cred[w][nt*16 + l16] = v;
    }
    __syncthreads();
    if (tid < 64)
        atomicAdd(&imp[b*T_ + k0 + tid],
                  cred[0][tid] + cred[1][tid] + cred[2][tid] + cred[3][tid]);
}

// ---------------- mask finalize: cm, loss, survivor count ----------------
__global__ __launch_bounds__(256) void mask_finalize(
    const float* __restrict__ imp, const float* __restrict__ amask,
    const float* __restrict__ prot, const float* __restrict__ thr,
    float* __restrict__ mask_out, float* __restrict__ loss_out,
    int* __restrict__ nsurv)
{
    int i = blockIdx.x * 256 + threadIdx.x;
    float impv = imp[i] * (1.0f / (float)(H_ * T_));
    float pm = (impv >= thr[0]) ? 1.f : 0.f;
    if (prot[i] > 0.f) pm = 1.f;
    float cm = amask[i] * pm;
    mask_out[i] = cm;
    if (i == 0) loss_out[0] = 0.f;
    unsigned long long bal = __ballot(cm != 0.f);
    int cnt = __popcll(bal);
    __shared__ int bs;
    if (threadIdx.x == 0) bs = 0;
    __syncthreads();
    if ((threadIdx.x & 63) == 0 && cnt) atomicAdd(&bs, cnt);
    __syncthreads();
    if (threadIdx.x == 0 && bs) atomicAdd(nsurv, bs);
}

// ================== consolidated DENSE tail (flagged; gsync barriers) ==================
// Merges the 9 dense-path launches (cvt3, gemm<3>, attn_full, gemm<4>, ln,
// gemm<1>, gemm<2>, gemm<1>, gemm<2>) into ONE kernel that early-exits when
// nsurv==0 (the benchmarked path). The spin barrier only runs on the dense
// path. Grid 256 x 256 thr, 32 KiB LDS: at 176 VGPR each CU holds >=2 blocks
// -> capacity >=512 >= 256 -> all blocks co-resident, no deadlock.
// Hot path cost: one ~1-2 us stub instead of nine.

static __device__ void cvt3_body(
        const float* __restrict__ cprojw, const float* __restrict__ fcw,
        const float* __restrict__ fcpw,
        unsigned short* __restrict__ wproj, unsigned short* __restrict__ wfc,
        unsigned short* __restrict__ wfcp)
{
    const int total = 9*C_*C_/4;
    const int n1 = C_*C_/4;
    const int n2 = n1 + C_*C_;
    for (int i = blockIdx.x * 256 + threadIdx.x; i < total; i += gridDim.x * 256) {
        const float* src; unsigned short* dst; int j;
        if (i < n1)      { src = cprojw; dst = wproj; j = i; }
        else if (i < n2) { src = fcw;    dst = wfc;   j = i - n1; }
        else             { src = fcpw;   dst = wfcp;  j = i - n2; }
        float4 v = ((const float4*)src)[j];
        u16v4 o = { f2bf(v.x), f2bf(v.y), f2bf(v.z), f2bf(v.w) };
        *(u16v4*)(dst + (size_t)j*4) = o;
    }
}

// EPI: 1 = bias + exact GELU -> bf16 ; 2 = bias(opt) + fp32 residual -> fp32
//      3 = bias -> bf16 head-major qkv scatter (q pre-scaled by QSCALE)
//      4 = bias + (res + v)*cm -> fp32
template<int EPI>
static __device__ void gemm_body(
    unsigned short* As, unsigned short* Bs,
    const unsigned short* __restrict__ A,
    const unsigned short* __restrict__ Bw,
    const float* __restrict__ bias,
    const float* __restrict__ res,
    float* __restrict__ Cout, unsigned short* __restrict__ Cbf,
    int K, int lda, int ldb, int ldc, int ncoff,
    const float* __restrict__ cmv,
    unsigned short* __restrict__ qh, unsigned short* __restrict__ kh,
    unsigned short* __restrict__ vh,
    int nbx, int nby)
{
    int tid = threadIdx.x;
    int w = tid >> 6, lane = tid & 63, quad = lane >> 4, l16 = lane & 15;
    int wr = w >> 1, wc = w & 1;

    int nvb = nbx * nby;
    int vb0 = blockIdx.x;
    int vstride = gridDim.x;

    for (int vb = vb0; vb < nvb; vb += vstride) {
        int n0 = (vb % nbx) * 128;
        int m0 = (vb / nbx) * 128;

        size_t offA[4], offB[4];
        #pragma unroll
        for (int j = 0; j < 4; j++) {
            int ci = j*256 + tid;
            int mr = ci >> 3, kcs = ci & 7;
            int kc = kcs ^ (mr & 7);
            offA[j] = (size_t)(m0 + mr) * lda + kc*8;
            offB[j] = (size_t)(n0 + mr) * ldb + kc*8;
        }

        f4v acc[4][4];
        #pragma unroll
        for (int i = 0; i < 4; i++)
            #pragma unroll
            for (int j = 0; j < 4; j++) { acc[i][j][0]=0.f; acc[i][j][1]=0.f; acc[i][j][2]=0.f; acc[i][j][3]=0.f; }

        for (int k0 = 0; k0 < K; k0 += 64) {
            __syncthreads();
            #pragma unroll
            for (int j = 0; j < 4; j++) {
                gload_lds16(A  + offA[j] + k0, &As[(j*256 + (w<<6))*8]);
                gload_lds16(Bw + offB[j] + k0, &Bs[(j*256 + (w<<6))*8]);
            }
            __syncthreads();
            #pragma unroll
            for (int c = 0; c < 2; c++) {
                s8v af[4], bf[4];
                int sw = ((c<<2) + quad) ^ (l16 & 7);
                #pragma unroll
                for (int i = 0; i < 4; i++) {
                    int mr = wr*64 + i*16 + l16;
                    af[i] = *(const s8v*)&As[mr*64 + sw*8];
                    int nr = wc*64 + i*16 + l16;
                    bf[i] = *(const s8v*)&Bs[nr*64 + sw*8];
                }
                #pragma unroll
                for (int i = 0; i < 4; i++)
                    #pragma unroll
                    for (int j = 0; j < 4; j++)
                        acc[i][j] = __builtin_amdgcn_mfma_f32_16x16x32_bf16(af[i], bf[j], acc[i][j], 0, 0, 0);
            }
        }

        #pragma unroll
        for (int j = 0; j < 4; j++) {
            int ncol = n0 + wc*64 + j*16 + l16;
            float bv = bias ? bias[ncol] : 0.f;
            int hh = 0, dd = 0;
            bool qsec = false;
            unsigned short* basep = nullptr;
            if (EPI == 3) {
                int ncolg = ncol + ncoff;
                int sec = ncolg >> 10;
                int hn = ncolg & 1023;
                hh = hn >> 6; dd = hn & 63;
                basep = (sec == 0) ? qh : (sec == 1) ? kh : vh;
                qsec = (sec == 0);
            }
            #pragma unroll
            for (int i = 0; i < 4; i++) {
                #pragma unroll
                for (int reg = 0; reg < 4; reg++) {
                    int m = m0 + wr*64 + i*16 + quad*4 + reg;
                    float v = acc[i][j][reg] + bv;
                    if (EPI == 1) {
                        v = 0.5f * v * (1.0f + erff(v * 0.70710678118654752f));
                        Cbf[(size_t)m*ldc + ncol] = f2bf(v);
                    } else if (EPI == 2) {
                        Cout[(size_t)m*ldc + ncol] = v + res[(size_t)m*ldc + ncol];
                    } else if (EPI == 3) {
                        if (qsec) v *= QSCALE;
                        int bb = m >> 11, t = m & 2047;
                        basep[(((size_t)(bb*H_ + hh))*T_ + t)*64 + dd] = f2bf(v);
                    } else if (EPI == 4) {
                        Cout[(size_t)m*ldc + ncol] = (res[(size_t)m*ldc + ncol] + v) * cmv[m];
                    }
                }
            }
        }
        __syncthreads();
    }
}

static __device__ void attn_full_body(unsigned short* sm,
    const unsigned short* __restrict__ qh, const unsigned short* __restrict__ kh,
    const unsigned short* __restrict__ vh, const float* __restrict__ amask,
    unsigned short* __restrict__ y)
{
    // layout in sm (shorts): Ks[64*72] | Vt[64*72] | Ps[4*16*72] | mks(64 fl)
    unsigned short* Ks = sm;
    unsigned short* Vt = sm + 64*72;
    unsigned short* Ps = sm + 2*64*72;
    float* mks = (float*)(sm + 2*64*72 + 4*16*72);

    int tid = threadIdx.x;
    int w = tid >> 6, lane = tid & 63, quad = lane >> 4, l16 = lane & 15;
    int nqt = T_ / 64;

    for (int vb = blockIdx.x; vb < B_*H_*nqt; vb += gridDim.x) {
        int qt = vb % nqt;
        int bh = vb / nqt;
        int b = bh >> 4, h = bh & 15;
        int q0 = qt * 64;

        const unsigned short* qp = qh + (size_t)bh * T_ * 64;
        const unsigned short* kp = kh + (size_t)bh * T_ * 64;
        const unsigned short* vp = vh + (size_t)bh * T_ * 64;

        int qrow = q0 + 16*w + l16;
        s8v aQ0 = *(const s8v*)(qp + (size_t)qrow*64 + quad*8);
        s8v aQ1 = *(const s8v*)(qp + (size_t)qrow*64 + 32 + quad*8);

        int qwmax = q0 + 16*w + 15;
        int ntiles = qt + 1;
        int qg = q0 + 16*w + quad*4;

        float lrow[4] = {0.f, 0.f, 0.f, 0.f};
        for (int it = 0; it < ntiles; ++it) {
            int k0 = it * 64;
            __syncthreads();
            for (int cid = tid; cid < 512; cid += 256) {
                int row = cid >> 3, ch = cid & 7;
                *(s8v*)&Ks[row*72 + ch*8] = *(const s8v*)(kp + (size_t)(k0+row)*64 + ch*8);
            }
            if (tid < 64) mks[tid] = amask[b*T_ + k0 + tid];
            __syncthreads();
            if (k0 > qwmax) continue;
            f4v accS[4];
            #pragma unroll
            for (int nt = 0; nt < 4; nt++) { accS[nt][0]=0.f; accS[nt][1]=0.f; accS[nt][2]=0.f; accS[nt][3]=0.f; }
            #pragma unroll
            for (int nt = 0; nt < 4; nt++) {
                s8v b0 = *(const s8v*)&Ks[(nt*16 + l16)*72 + quad*8];
                s8v b1 = *(const s8v*)&Ks[(nt*16 + l16)*72 + 32 + quad*8];
                accS[nt] = __builtin_amdgcn_mfma_f32_16x16x32_bf16(aQ0, b0, accS[nt], 0, 0, 0);
                accS[nt] = __builtin_amdgcn_mfma_f32_16x16x32_bf16(aQ1, b1, accS[nt], 0, 0, 0);
            }
            #pragma unroll
            for (int nt = 0; nt < 4; nt++) {
                int kg = k0 + nt*16 + l16;
                float mkv = mks[nt*16 + l16];
                #pragma unroll
                for (int reg = 0; reg < 4; reg++) {
                    bool val = (kg <= qg + reg) && (mkv != 0.f);
                    float e = fexp2(accS[nt][reg]);
                    lrow[reg] += val ? e : 0.f;
                }
            }
        }
        float linv[4];
        #pragma unroll
        for (int reg = 0; reg < 4; reg++) {
            float v = lrow[reg];
            v += __shfl_xor(v, 1); v += __shfl_xor(v, 2);
            v += __shfl_xor(v, 4); v += __shfl_xor(v, 8);
            linv[reg] = (v > 0.f) ? 1.0f / v : 0.f;
        }

        f4v accO[4];
        #pragma unroll
        for (int nt = 0; nt < 4; nt++) { accO[nt][0]=0.f; accO[nt][1]=0.f; accO[nt][2]=0.f; accO[nt][3]=0.f; }

        for (int it = 0; it < ntiles; ++it) {
            int k0 = it * 64;
            __syncthreads();
            for (int cid = tid; cid < 512; cid += 256) {
                int row = cid >> 3, ch = cid & 7;
                s8v kv = *(const s8v*)(kp + (size_t)(k0+row)*64 + ch*8);
                *(s8v*)&Ks[row*72 + ch*8] = kv;
                s8v vv = *(const s8v*)(vp + (size_t)(k0+row)*64 + ch*8);
                #pragma unroll
                for (int j = 0; j < 8; j++) Vt[(ch*8 + j)*72 + row] = (unsigned short)vv[j];
            }
            if (tid < 64) mks[tid] = amask[b*T_ + k0 + tid];
            __syncthreads();
            if (k0 > qwmax) continue;
            f4v accS[4];
            #pragma unroll
            for (int nt = 0; nt < 4; nt++) { accS[nt][0]=0.f; accS[nt][1]=0.f; accS[nt][2]=0.f; accS[nt][3]=0.f; }
            #pragma unroll
            for (int nt = 0; nt < 4; nt++) {
                s8v b0 = *(const s8v*)&Ks[(nt*16 + l16)*72 + quad*8];
                s8v b1 = *(const s8v*)&Ks[(nt*16 + l16)*72 + 32 + quad*8];
                accS[nt] = __builtin_amdgcn_mfma_f32_16x16x32_bf16(aQ0, b0, accS[nt], 0, 0, 0);
                accS[nt] = __builtin_amdgcn_mfma_f32_16x16x32_bf16(aQ1, b1, accS[nt], 0, 0, 0);
            }
            #pragma unroll
            for (int nt = 0; nt < 4; nt++) {
                int kg = k0 + nt*16 + l16;
                float mkv = mks[nt*16 + l16];
                #pragma unroll
                for (int reg = 0; reg < 4; reg++) {
                    bool val = (kg <= qg + reg) && (mkv != 0.f);
                    float p = val ? fexp2(accS[nt][reg]) * linv[reg] : 0.f;
                    Ps[(w*16 + quad*4 + reg)*72 + nt*16 + l16] = f2bf(p);
                }
            }
            s8v aP0 = *(const s8v*)&Ps[(w*16 + l16)*72 + quad*8];
            s8v aP1 = *(const s8v*)&Ps[(w*16 + l16)*72 + 32 + quad*8];
            #pragma unroll
            for (int nt = 0; nt < 4; nt++) {
                s8v bv0 = *(const s8v*)&Vt[(nt*16 + l16)*72 + quad*8];
                s8v bv1 = *(const s8v*)&Vt[(nt*16 + l16)*72 + 32 + quad*8];
                accO[nt] = __builtin_amdgcn_mfma_f32_16x16x32_bf16(aP0, bv0, accO[nt], 0, 0, 0);
                accO[nt] = __builtin_amdgcn_mfma_f32_16x16x32_bf16(aP1, bv1, accO[nt], 0, 0, 0);
            }
        }
        #pragma unroll
        for (int nt = 0; nt < 4; nt++) {
            #pragma unroll
            for (int reg = 0; reg < 4; reg++) {
                int q = q0 + 16*w + quad*4 + reg;
                y[((size_t)(b*T_ + q))*C_ + h*64 + nt*16 + l16] = f2bf(accO[nt][reg]);
            }
        }
        __syncthreads();
    }
}

static __device__ void ln_body(const float* __restrict__ x,
        const float* __restrict__ w, const float* __restrict__ b,
        unsigned short* __restrict__ out, int nrows)
{
    int tid = threadIdx.x;
    __shared__ float rs[4], rss[4];
    __shared__ float smu, srstd;
    int wave = tid >> 6, lane = tid & 63;
    for (int row = blockIdx.x; row < nrows; row += gridDim.x) {
        const float4* xr = (const float4*)(x + (size_t)row * C_);
        float4 v = xr[tid];
        float s  = v.x + v.y + v.z + v.w;
        float ss = v.x*v.x + v.y*v.y + v.z*v.z + v.w*v.w;
        #pragma unroll
        for (int off = 32; off > 0; off >>= 1) {
            s  += __shfl_down(s,  off, 64);
            ss += __shfl_down(ss, off, 64);
        }
        if (lane == 0) { rs[wave] = s; rss[wave] = ss; }
        __syncthreads();
        if (tid == 0) {
            float S  = rs[0]+rs[1]+rs[2]+rs[3];
            float SS = rss[0]+rss[1]+rss[2]+rss[3];
            float mu = S * (1.0f/C_);
            float var = SS * (1.0f/C_) - mu*mu;
            smu = mu; srstd = rsqrtf(var + 1e-5f);
        }
        __syncthreads();
        float mu = smu, rstd = srstd;
        float4 wv = ((const float4*)w)[tid];
        float4 bv = ((const float4*)b)[tid];
        u16v4 o;
        o.x = f2bf((v.x-mu)*rstd*wv.x + bv.x);
        o.y = f2bf((v.y-mu)*rstd*wv.y + bv.y);
        o.z = f2bf((v.z-mu)*rstd*wv.z + bv.z);
        o.w = f2bf((v.w-mu)*rstd*wv.w + bv.w);
        *(u16v4*)(out + (size_t)row * C_ + tid*4) = o;
        __syncthreads();
    }
}

__global__ __launch_bounds__(256) void dense_tail(
    const float* __restrict__ x, const float* __restrict__ amask,
    const float* __restrict__ cproj_w, const float* __restrict__ cproj_b,
    const float* __restrict__ ln2w, const float* __restrict__ ln2b,
    const float* __restrict__ fcw, const float* __restrict__ fcb,
    const float* __restrict__ fcpw, const float* __restrict__ fcpb,
    const float* __restrict__ cattn_b,
    unsigned short* __restrict__ wqkv, unsigned short* __restrict__ wproj,
    unsigned short* __restrict__ wfc, unsigned short* __restrict__ wfcp,
    unsigned short* __restrict__ hbuf,
    unsigned short* __restrict__ qh, unsigned short* __restrict__ kh,
    unsigned short* __restrict__ vh, unsigned short* __restrict__ cbuf,
    float* __restrict__ out_x, float* __restrict__ out_mask,
    int* __restrict__ nsurv)
{
    if (nsurv[0] == 0) return;           // hot path: single cheap stub

    __shared__ unsigned short smem[2*128*64];   // 32 KiB, reused across phases
    unsigned short* As = smem;
    unsigned short* Bs = smem + 128*64;
    int* bar = nsurv + 4;                // [cnt, gen], zeroed by prep
    const int nblk = gridDim.x;

    // cvt3 and the V-projection are mutually independent: no barrier between
    cvt3_body(cproj_w, fcw, fcpw, wproj, wfc, wfcp);
    gemm_body<3>(As, Bs, hbuf, wqkv + (size_t)2048*C_, cattn_b + 2048,
                 nullptr, nullptr, nullptr, C_, C_, C_, 0, 2048, nullptr,
                 qh, kh, vh, 8, 64);
    gsync(bar, nblk);
    attn_full_body(smem, qh, kh, vh, amask, hbuf);
    gsync(bar, nblk);
    gemm_body<4>(As, Bs, hbuf, wproj, cproj_b, x, out_x, nullptr,
                 C_, C_, C_, C_, 0, out_mask, nullptr, nullptr, nullptr, 8, 64);
    gsync(bar, nblk);
    ln_body(out_x, ln2w, ln2b, hbuf, NROWS);
    gsync(bar, nblk);
    for (int j = 0; j < 2; j++) {
        gemm_body<1>(As, Bs, hbuf, wfc + (size_t)j*2048*C_, fcb + j*2048,
                     nullptr, nullptr, cbuf, C_, C_, C_, 2048, 0, nullptr,
                     nullptr, nullptr, nullptr, 16, 64);
        gsync(bar, nblk);
        gemm_body<2>(As, Bs, cbuf, wfcp + (size_t)j*2048, (j == 0) ? fcpb : nullptr,
                     out_x, out_x, nullptr, 2048, 2048, 4*C_, C_, 0, nullptr,
                     nullptr, nullptr, nullptr, 8, 64);
        gsync(bar, nblk);
    }
}

// ---------------- all-pruned fast path: one-row MLP + broadcast ----------------
__global__ __launch_bounds__(256) void ap_fc(const int* __restrict__ nsurv,
        const float* __restrict__ ln2b, const float* __restrict__ fcw,
        const float* __restrict__ fcb, float* __restrict__ abuf)
{
    if (nsurv[0] != 0) return;
    int j = blockIdx.x * 4 + (threadIdx.x >> 6);
    int lane = threadIdx.x & 63;
    const float4* wr = (const float4*)(fcw + (size_t)j * C_);
    const float4* bb = (const float4*)ln2b;
    float s = 0.f;
    #pragma unroll
    for (int k = 0; k < 4; k++) {
        float4 a = bb[lane + 64*k];
        float4 wv = wr[lane + 64*k];
        s += a.x*wv.x + a.y*wv.y + a.z*wv.z + a.w*wv.w;
    }
    #pragma unroll
    for (int off = 32; off > 0; off >>= 1) s += __shfl_down(s, off, 64);
    if (lane == 0) {
        float v = fcb[j] + s;
        abuf[j] = 0.5f * v * (1.0f + erff(v * 0.70710678118654752f));
    }
}

__global__ __launch_bounds__(256) void ap_fcp(const int* __restrict__ nsurv,
        const float* __restrict__ abuf, const float* __restrict__ fcpw,
        const float* __restrict__ fcpb, float* __restrict__ rowbuf)
{
    if (nsurv[0] != 0) return;
    int c = blockIdx.x * 4 + (threadIdx.x >> 6);
    int lane = threadIdx.x & 63;
    const float4* wr = (const float4*)(fcpw + (size_t)c * (4*C_));
    const float4* ab = (const float4*)abuf;
    float s = 0.f;
    #pragma unroll
    for (int k = 0; k < 16; k++) {
        float4 a = ab[lane + 64*k];
        float4 wv = wr[lane + 64*k];
        s += a.x*wv.x + a.y*wv.y + a.z*wv.z + a.w*wv.w;
    }
    #pragma unroll
    for (int off = 32; off > 0; off >>= 1) s += __shfl_down(s, off, 64);
    if (lane == 0) rowbuf[c] = fcpb[c] + s;
}

__global__ __launch_bounds__(256) void ap_bcast(const int* __restrict__ nsurv,
        const float* __restrict__ rowbuf, float* __restrict__ out_x)
{
    if (nsurv[0] != 0) return;
    float4 v = ((const float4*)rowbuf)[threadIdx.x];
    for (int r = blockIdx.x; r < NROWS; r += gridDim.x)
        ((float4*)(out_x + (size_t)r * C_))[threadIdx.x] = v;
}

extern "C" void kernel_launch(void* const* d_in, const int* in_sizes, int n_in,
                              void* d_out, int out_size, void* d_ws, size_t ws_size,
                              hipStream_t stream) {
    const float* x       = (const float*)d_in[0];
    const float* amask   = (const float*)d_in[1];
    const float* prot    = (const float*)d_in[2];
    const float* ln1w    = (const float*)d_in[3];
    const float* ln1b    = (const float*)d_in[4];
    const float* cattn_w = (const float*)d_in[5];
    const float* cattn_b = (const float*)d_in[6];
    const float* cproj_w = (const float*)d_in[7];
    const float* cproj_b = (const float*)d_in[8];
    const float* ln2w    = (const float*)d_in[9];
    const float* ln2b    = (const float*)d_in[10];
    const float* fcw     = (const float*)d_in[11];
    const float* fcb     = (const float*)d_in[12];
    const float* fcpw    = (const float*)d_in[13];
    const float* fcpb    = (const float*)d_in[14];
    const float* thr     = (const float*)d_in[15];

    unsigned short* wqkv  = (unsigned short*)d_ws;
    unsigned short* wproj = wqkv  + (size_t)3*C_*C_;
    unsigned short* wfc   = wproj + (size_t)C_*C_;
    unsigned short* wfcp  = wfc   + (size_t)4*C_*C_;
    unsigned short* hbuf  = wfcp  + (size_t)4*C_*C_;
    unsigned short* qh    = hbuf  + (size_t)NROWS*C_;
    unsigned short* kh    = qh    + (size_t)NROWS*C_;
    unsigned short* vh    = kh    + (size_t)NROWS*C_;
    unsigned short* cbuf  = qh;                        // fc chunk out (dense path)
    float* imp    = (float*)(vh + (size_t)NROWS*C_);
    int*   nsurv  = (int*)(imp + NROWS);
    float* abuf   = (float*)(nsurv + 8);
    float* rowbuf = abuf + 4*C_;
    float* linvbuf = rowbuf + C_;                      // 64*2048 fp32

    float* out_x    = (float*)d_out;
    float* out_mask = out_x + (size_t)NROWS*C_;
    float* out_loss = out_mask + NROWS;

    // prep: LN1 + qkv weight cvt + zero imp/nsurv (incl. barrier counters)
    hipLaunchKernelGGL(prep_kernel, dim3(NROWS), dim3(256), 0, stream,
                       x, ln1w, ln1b, hbuf, cattn_w, wqkv, imp, nsurv);
    // QK GEMM (N = 2048) -> qh/kh head-major (q pre-scaled by QSCALE)
    hipLaunchKernelGGL(gemm_qk_8ph, dim3(256), dim3(512), 0, stream,
                       hbuf, wqkv, cattn_b, qh, kh);
    // attention: two barrier-free streaming passes (round-4 proven-best)
    hipLaunchKernelGGL(attn_rowsum, dim3(64*32), dim3(256), 0, stream,
                       qh, kh, amask, linvbuf);
    hipLaunchKernelGGL(attn_colsum, dim3(64*32), dim3(256), 0, stream,
                       qh, kh, amask, linvbuf, imp);
    hipLaunchKernelGGL(mask_finalize, dim3(NROWS/256), dim3(256), 0, stream,
                       imp, amask, prot, thr, out_mask, out_loss, nsurv);

    // ---- dense fallback path: ONE flagged kernel (gsync only when taken) ----
    hipLaunchKernelGGL(dense_tail, dim3(256), dim3(256), 0, stream,
                       x, amask, cproj_w, cproj_b, ln2w, ln2b, fcw, fcb,
                       fcpw, fcpb, cattn_b, wqkv, wproj, wfc, wfcp, hbuf,
                       qh, kh, vh, cbuf, out_x, out_mask, nsurv);

    // ---- all-pruned fast path (early-exit when nsurv != 0) ----
    hipLaunchKernelGGL(ap_fc,    dim3(4*C_/4), dim3(256), 0, stream, nsurv, ln2b, fcw, fcb, abuf);
    hipLaunchKernelGGL(ap_fcp,   dim3(C_/4),   dim3(256), 0, stream, nsurv, abuf, fcpw, fcpb, rowbuf);
    hipLaunchKernelGGL(ap_bcast, dim3(512),    dim3(256), 0, stream, nsurv, rowbuf, out_x);
}